// Round 1
// baseline (1382.496 us; speedup 1.0000x reference)
//
#include <hip/hip_runtime.h>
#include <math.h>

#define BB 2
#define NN 2048
#define KK 256
#define DD 768
#define HH 150
#define LL 11
#define NBINS 10
#define CH 50
#define JT 2

// ---------------- transpose w_h -> w_h_t[n][m] ----------------
__global__ void k_transpose_wh(const float* __restrict__ w_h, float* __restrict__ w_h_t) {
  int idx = blockIdx.x * 256 + threadIdx.x;
  if (idx < HH * HH) {
    int m = idx / HH, n = idx - m * HH;
    w_h_t[n * HH + m] = w_h[m * HH + n];
  }
}

// ---------------- proj: left/right/ss ----------------
__global__ __launch_bounds__(256) void k_proj(
    const float* __restrict__ upd,
    const float* __restrict__ w_left, const float* __restrict__ b_left,
    const float* __restrict__ w_right, const float* __restrict__ b_right,
    const float* __restrict__ pr_w, const float* __restrict__ pr_b,
    float* __restrict__ left, float* __restrict__ right, float* __restrict__ ss)
{
  const int ROWS = 4;
  int row0 = blockIdx.x * ROWS;                 // in [0, B*K)
  __shared__ float u[ROWS][DD];
  __shared__ float red[ROWS][256];
  for (int idx = threadIdx.x; idx < ROWS * DD; idx += 256) {
    int r = idx / DD, d = idx - r * DD;
    u[r][d] = upd[(size_t)(row0 + r) * DD + d];
  }
  __syncthreads();
  int t = threadIdx.x;
  if (t < HH) {
    float accL[ROWS] = {0.f, 0.f, 0.f, 0.f};
    float accR[ROWS] = {0.f, 0.f, 0.f, 0.f};
    #pragma unroll 4
    for (int d = 0; d < DD; ++d) {
      float wl = w_left[d * HH + t];
      float wr = w_right[d * HH + t];
      #pragma unroll
      for (int r = 0; r < ROWS; ++r) {
        accL[r] = fmaf(u[r][d], wl, accL[r]);
        accR[r] = fmaf(u[r][d], wr, accR[r]);
      }
    }
    #pragma unroll
    for (int r = 0; r < ROWS; ++r) {
      left[(size_t)(row0 + r) * HH + t]  = accL[r] + b_left[t];
      right[(size_t)(row0 + r) * HH + t] = accR[r] + b_right[t];
    }
  }
  // pruner score ss = u . pr_w + pr_b
  float p[ROWS] = {0.f, 0.f, 0.f, 0.f};
  for (int d = t; d < DD; d += 256) {
    float w = pr_w[d];
    #pragma unroll
    for (int r = 0; r < ROWS; ++r) p[r] = fmaf(u[r][d], w, p[r]);
  }
  #pragma unroll
  for (int r = 0; r < ROWS; ++r) red[r][t] = p[r];
  __syncthreads();
  for (int s = 128; s > 0; s >>= 1) {
    if (t < s) {
      #pragma unroll
      for (int r = 0; r < ROWS; ++r) red[r][t] += red[r][t + s];
    }
    __syncthreads();
  }
  if (t == 0) {
    #pragma unroll
    for (int r = 0; r < ROWS; ++r) ss[row0 + r] = red[r][0] + pr_b[0];
  }
}

// ---------------- pair scores: rel[b,i,j,l] ----------------
__global__ __launch_bounds__(256, 2) void k_pair(
    const float* __restrict__ left, const float* __restrict__ right,
    const float* __restrict__ ss, const int* __restrict__ span_begin,
    const float* __restrict__ dist_emb,
    const float* __restrict__ w_h_t, const float* __restrict__ b_h,
    const float* __restrict__ w_out, const float* __restrict__ b_out,
    float* __restrict__ rel)
{
  int b = blockIdx.x / KK;
  int i = blockIdx.x - b * KK;
  int j = threadIdx.x;

  __shared__ float left_lds[HH];
  __shared__ float demb[NBINS * HH];
  __shared__ float rbuf[KK][CH];

  for (int idx = threadIdx.x; idx < HH; idx += 256)
    left_lds[idx] = left[(size_t)(b * KK + i) * HH + idx];
  for (int idx = threadIdx.x; idx < NBINS * HH; idx += 256)
    demb[idx] = dist_emb[idx];

  int sb_i = span_begin[b * KK + i];
  int sb_j = span_begin[b * KK + j];
  int bin = sb_j - sb_i; if (bin < 0) bin = -bin; if (bin > NBINS - 1) bin = NBINS - 1;

  float h0[HH];
  #pragma unroll
  for (int c = 0; c < 3; ++c) {
    __syncthreads();
    for (int idx = threadIdx.x; idx < KK * CH; idx += 256) {
      int jj = idx / CH, m = idx - jj * CH;
      rbuf[jj][m] = right[(size_t)(b * KK + jj) * HH + c * CH + m];
    }
    __syncthreads();
    #pragma unroll
    for (int m = 0; m < CH; ++m) {
      int mm = c * CH + m;
      h0[mm] = fmaxf(left_lds[mm] + rbuf[j][m] + demb[bin * HH + mm], 0.f);
    }
  }

  float ssum = ss[b * KK + i] + ss[b * KK + j];
  float out[LL];
  #pragma unroll
  for (int l = 0; l < LL; ++l) out[l] = b_out[l] + ssum;

  for (int n = 0; n < HH; ++n) {
    const float* wr = w_h_t + n * HH;      // uniform across lanes -> scalar loads
    float a0 = 0.f, a1 = 0.f, a2 = 0.f, a3 = 0.f;
    #pragma unroll
    for (int m = 0; m < 148; m += 4) {
      a0 = fmaf(h0[m + 0], wr[m + 0], a0);
      a1 = fmaf(h0[m + 1], wr[m + 1], a1);
      a2 = fmaf(h0[m + 2], wr[m + 2], a2);
      a3 = fmaf(h0[m + 3], wr[m + 3], a3);
    }
    a0 = fmaf(h0[148], wr[148], a0);
    a1 = fmaf(h0[149], wr[149], a1);
    float h1 = (a0 + a1) + (a2 + a3) + b_h[n];
    h1 = fmaxf(h1, 0.f);
    #pragma unroll
    for (int l = 0; l < LL; ++l) out[l] = fmaf(h1, w_out[n * LL + l], out[l]);
  }

  float* dst = rel + ((size_t)(b * KK + i) * KK + j) * LL;
  #pragma unroll
  for (int l = 0; l < LL; ++l) dst[l] = out[l];
}

// ---------------- ctxt[b,j,d] = (1/len) sum_i upd[b,i,d] * (probs[b,i,j,:] . a_w[:,d]) ----------------
__global__ __launch_bounds__(256) void k_ctxt(
    const float* __restrict__ upd, const float* __restrict__ rel,
    const float* __restrict__ mask, const float* __restrict__ a_w,
    const float* __restrict__ span_len, float* __restrict__ ctxt)
{
  int b = blockIdx.x / (KK / JT);
  int j0 = (blockIdx.x - b * (KK / JT)) * JT;
  int t = threadIdx.x;
  float aw[LL][3];
  #pragma unroll
  for (int l = 0; l < LL; ++l)
    #pragma unroll
    for (int c = 0; c < 3; ++c)
      aw[l][c] = a_w[l * DD + c * 256 + t];
  float acc[JT][3] = {};
  __shared__ float p[16][JT][LL + 1];
  for (int i0 = 0; i0 < KK; i0 += 16) {
    __syncthreads();
    for (int idx = t; idx < 16 * JT * LL; idx += 256) {
      int il = idx / (JT * LL);
      int r  = idx - il * (JT * LL);
      int jt = r / LL, l = r - jt * LL;
      size_t pij = ((size_t)(b * KK + i0 + il)) * KK + (j0 + jt);
      float mv = mask[pij];
      float v  = rel[pij * LL + l];
      p[il][jt][l] = fmaxf(v, 0.f) * mv;
    }
    __syncthreads();
    for (int il = 0; il < 16; ++il) {
      int i = i0 + il;
      size_t ub = ((size_t)(b * KK + i)) * DD;
      float u0 = upd[ub + t];
      float u1 = upd[ub + 256 + t];
      float u2 = upd[ub + 512 + t];
      #pragma unroll
      for (int jt = 0; jt < JT; ++jt) {
        float pa0 = 0.f, pa1 = 0.f, pa2 = 0.f;
        #pragma unroll
        for (int l = 0; l < LL; ++l) {
          float pv = p[il][jt][l];
          pa0 = fmaf(pv, aw[l][0], pa0);
          pa1 = fmaf(pv, aw[l][1], pa1);
          pa2 = fmaf(pv, aw[l][2], pa2);
        }
        acc[jt][0] = fmaf(u0, pa0, acc[jt][0]);
        acc[jt][1] = fmaf(u1, pa1, acc[jt][1]);
        acc[jt][2] = fmaf(u2, pa2, acc[jt][2]);
      }
    }
  }
  float inv = 1.f / span_len[b];
  #pragma unroll
  for (int jt = 0; jt < JT; ++jt) {
    size_t base = ((size_t)(b * KK + j0 + jt)) * DD;
    ctxt[base + t]       = acc[jt][0] * inv;
    ctxt[base + 256 + t] = acc[jt][1] * inv;
    ctxt[base + 512 + t] = acc[jt][2] * inv;
  }
}

// ---------------- gate + blend: upd_out = g*upd + (1-g)*ctxt ----------------
__global__ __launch_bounds__(256) void k_gate(
    const float* __restrict__ upd, const float* __restrict__ ctxt,
    const float* __restrict__ gate_w, const float* __restrict__ gate_b,
    float* __restrict__ upd_out)
{
  const int RB = 8;
  int rb = blockIdx.x / 3;
  int cb = blockIdx.x - rb * 3;
  int row0 = rb * RB;
  int c = cb * 256 + threadIdx.x;
  float acc[RB] = {};
  #pragma unroll 4
  for (int m = 0; m < DD; ++m) {
    float w = gate_w[(size_t)m * DD + c];
    #pragma unroll
    for (int r = 0; r < RB; ++r)
      acc[r] = fmaf(upd[(size_t)(row0 + r) * DD + m], w, acc[r]);
  }
  #pragma unroll 4
  for (int m = 0; m < DD; ++m) {
    float w = gate_w[(size_t)(DD + m) * DD + c];
    #pragma unroll
    for (int r = 0; r < RB; ++r)
      acc[r] = fmaf(ctxt[(size_t)(row0 + r) * DD + m], w, acc[r]);
  }
  float gb = gate_b[c];
  #pragma unroll
  for (int r = 0; r < RB; ++r) {
    float x = acc[r] + gb;
    float g = 1.f / (1.f + expf(-x));
    float uv = upd[(size_t)(row0 + r) * DD + c];
    float cv = ctxt[(size_t)(row0 + r) * DD + c];
    upd_out[(size_t)(row0 + r) * DD + c] = g * uv + (1.f - g) * cv;
  }
}

// ---------------- scatter updated spans back ----------------
__global__ void k_scatter(const float* __restrict__ upd,
                          const int* __restrict__ prune_idx,
                          const float* __restrict__ span_len,
                          float* __restrict__ out_all)
{
  int b = blockIdx.x / KK;
  int k = blockIdx.x - b * KK;
  if ((float)k < span_len[b]) {
    int dst = prune_idx[b * KK + k];
    const float4* src = (const float4*)(upd + ((size_t)(b * KK + k)) * DD);
    float4* d = (float4*)(out_all + ((size_t)b * NN + dst) * DD);
    for (int idx = threadIdx.x; idx < DD / 4; idx += blockDim.x) d[idx] = src[idx];
  }
}

extern "C" void kernel_launch(void* const* d_in, const int* in_sizes, int n_in,
                              void* d_out, int out_size, void* d_ws, size_t ws_size,
                              hipStream_t stream)
{
  (void)in_sizes; (void)n_in; (void)out_size; (void)ws_size;
  const float* all_span = (const float*)d_in[0];
  const float* upd_in   = (const float*)d_in[1];
  const float* mask     = (const float*)d_in[2];
  const float* span_len = (const float*)d_in[3];
  const int*   span_beg = (const int*)d_in[4];
  const int*   prune    = (const int*)d_in[6];
  const float* w_left   = (const float*)d_in[7];
  const float* b_left   = (const float*)d_in[8];
  const float* w_right  = (const float*)d_in[9];
  const float* b_right  = (const float*)d_in[10];
  const float* dist_emb = (const float*)d_in[11];
  const float* w_h      = (const float*)d_in[12];
  const float* b_h      = (const float*)d_in[13];
  const float* w_out    = (const float*)d_in[14];
  const float* b_out    = (const float*)d_in[15];
  const float* a_w      = (const float*)d_in[16];
  const float* gate_w   = (const float*)d_in[17];
  const float* gate_b   = (const float*)d_in[18];
  const float* pr_w     = (const float*)d_in[19];
  const float* pr_b     = (const float*)d_in[20];

  float* out_all = (float*)d_out;                       // [B,N,D]
  float* out_upd = out_all + (size_t)BB * NN * DD;      // [B,K,D]
  float* out_rel = out_upd + (size_t)BB * KK * DD;      // [B,K,K,L]

  float* ws     = (float*)d_ws;
  float* left   = ws;                                   // B*K*H
  float* right  = left + (size_t)BB * KK * HH;          // B*K*H
  float* ssv    = right + (size_t)BB * KK * HH;         // B*K
  float* ctxt   = ssv + (size_t)BB * KK;                // B*K*D
  float* upd_ws = ctxt + (size_t)BB * KK * DD;          // B*K*D
  float* wht    = upd_ws + (size_t)BB * KK * DD;        // H*H

  hipMemcpyAsync(out_all, all_span, sizeof(float) * (size_t)BB * NN * DD,
                 hipMemcpyDeviceToDevice, stream);
  hipMemcpyAsync(out_upd, upd_in, sizeof(float) * (size_t)BB * KK * DD,
                 hipMemcpyDeviceToDevice, stream);
  k_transpose_wh<<<(HH * HH + 255) / 256, 256, 0, stream>>>(w_h, wht);

  k_proj<<<BB * KK / 4, 256, 0, stream>>>(out_upd, w_left, b_left, w_right, b_right,
                                          pr_w, pr_b, left, right, ssv);
  k_pair<<<BB * KK, 256, 0, stream>>>(left, right, ssv, span_beg, dist_emb,
                                      wht, b_h, w_out, b_out, out_rel);

  for (int p = 0; p < 2; ++p) {
    const float* cur = (p == 0) ? out_upd : upd_ws;
    float* nxt       = (p == 0) ? upd_ws  : out_upd;
    k_ctxt<<<BB * (KK / JT), 256, 0, stream>>>(cur, out_rel, mask, a_w, span_len, ctxt);
    k_gate<<<(BB * KK / 8) * 3, 256, 0, stream>>>(cur, ctxt, gate_w, gate_b, nxt);
    k_proj<<<BB * KK / 4, 256, 0, stream>>>(nxt, w_left, b_left, w_right, b_right,
                                            pr_w, pr_b, left, right, ssv);
    k_pair<<<BB * KK, 256, 0, stream>>>(left, right, ssv, span_beg, dist_emb,
                                        wht, b_h, w_out, b_out, out_rel);
  }
  k_scatter<<<BB * KK, 192, 0, stream>>>(out_upd, prune, span_len, out_all);
}

// Round 2
// 831.353 us; speedup vs baseline: 1.6629x; 1.6629x over previous
//
#include <hip/hip_runtime.h>
#include <math.h>

#define BB 2
#define NN 2048
#define KK 256
#define DD 768
#define HH 150
#define LL 11
#define NBINS 10
#define JT 2

#define KP 160          // padded K/N for MFMA tiles
#define RP 168          // h0/h1/wo row stride in shorts (bank-conflict pad)
#define WP 40           // wt_s k-slice row stride in shorts

typedef __attribute__((ext_vector_type(8))) short short8;
typedef __attribute__((ext_vector_type(4))) float f32x4;

__device__ inline unsigned f2bfu(float x) {
  unsigned u = __float_as_uint(x);
  unsigned r = ((u >> 16) & 1u) + 0x7fffu;
  return (u + r) >> 16;
}

// ---------------- prep: bf16 zero-padded transposed weights ----------------
// wt[n*160+k] = bf16(w_h[k*150+n])  (n<150,k<150 else 0)
// wo[n*160+k] = bf16(w_out[k*11+n]) (n<11, k<150 else 0)
__global__ void k_prep(const float* __restrict__ w_h, const float* __restrict__ w_out,
                       short* __restrict__ wt, short* __restrict__ wo) {
  int idx = blockIdx.x * 256 + threadIdx.x;
  if (idx < KP * KP) {
    int n = idx / KP, k = idx - n * KP;
    float v = (n < HH && k < HH) ? w_h[k * HH + n] : 0.f;
    wt[idx] = (short)f2bfu(v);
  }
  int idx2 = idx - KP * KP;
  if (idx2 >= 0 && idx2 < 16 * KP) {
    int n = idx2 / KP, k = idx2 - n * KP;
    float v = (n < LL && k < HH) ? w_out[k * LL + n] : 0.f;
    wo[idx2] = (short)f2bfu(v);
  }
}

// ---------------- proj: left/right/ss ----------------
__global__ __launch_bounds__(384) void k_proj(
    const float* __restrict__ upd,
    const float* __restrict__ w_left, const float* __restrict__ b_left,
    const float* __restrict__ w_right, const float* __restrict__ b_right,
    const float* __restrict__ pr_w, const float* __restrict__ pr_b,
    float* __restrict__ left, float* __restrict__ right, float* __restrict__ ss)
{
  int row0 = blockIdx.x * 2;
  __shared__ float u[2][DD];
  __shared__ float red[2][8];
  int t = threadIdx.x;
  for (int idx = t; idx < 2 * DD; idx += 384) {
    int r = idx / DD, d = idx - r * DD;
    u[r][d] = upd[(size_t)(row0 + r) * DD + d];
  }
  __syncthreads();
  int half = t / 192;
  int col = t - half * 192;
  if (col < HH) {
    const float* wm = half ? w_right : w_left;
    float a0 = 0.f, a1 = 0.f;
    #pragma unroll 4
    for (int d = 0; d < DD; ++d) {
      float wv = wm[d * HH + col];
      a0 = fmaf(u[0][d], wv, a0);
      a1 = fmaf(u[1][d], wv, a1);
    }
    float bb = half ? b_right[col] : b_left[col];
    float* dst = half ? right : left;
    dst[(size_t)(row0 + 0) * HH + col] = a0 + bb;
    dst[(size_t)(row0 + 1) * HH + col] = a1 + bb;
  }
  float p0 = 0.f, p1 = 0.f;
  for (int d = t; d < DD; d += 384) {
    float wv = pr_w[d];
    p0 = fmaf(u[0][d], wv, p0);
    p1 = fmaf(u[1][d], wv, p1);
  }
  #pragma unroll
  for (int off = 32; off > 0; off >>= 1) {
    p0 += __shfl_down(p0, off);
    p1 += __shfl_down(p1, off);
  }
  int l = t & 63, w = t >> 6;
  if (l == 0) { red[0][w] = p0; red[1][w] = p1; }
  __syncthreads();
  if (t == 0) {
    float s0 = pr_b[0], s1 = pr_b[0];
    #pragma unroll
    for (int k = 0; k < 6; ++k) { s0 += red[0][k]; s1 += red[1][k]; }
    ss[row0] = s0; ss[row0 + 1] = s1;
  }
}

// ---------------- pair scores via MFMA ----------------
// block: (b, i, jt) -> 128 j-rows. h0=relu(left_i+right_j+demb) bf16 in LDS,
// GEMM1 h0@w_h (K=N=160 padded, zero weights make pad inert), relu -> h1 in
// same LDS tile, GEMM2 h1@w_out (N=16 padded), epilogue adds ss_i+ss_j+b_out.
__global__ __launch_bounds__(256) void k_pair_mfma(
    const float* __restrict__ left, const float* __restrict__ right,
    const float* __restrict__ ss, const int* __restrict__ span_begin,
    const float* __restrict__ demb,
    const short* __restrict__ wt, const short* __restrict__ wo,
    const float* __restrict__ b_h, const float* __restrict__ b_out,
    float* __restrict__ rel)
{
  int b  = blockIdx.x >> 9;
  int r2 = blockIdx.x & 511;
  int i  = r2 >> 1;
  int j0 = (r2 & 1) * 128;

  __shared__ short h0[128][RP];      // 43008 B (h0 then h1)
  __shared__ short wt_s[KP][WP];     // 12800 B (reused as out staging)
  __shared__ short wo_s[16][RP];     //  5376 B
  __shared__ float left_s[152];
  __shared__ float bh_s[KP];
  __shared__ float ssj_s[128];
  __shared__ int   bins[128];

  int t = threadIdx.x;
  int l = t & 63, w = t >> 6;
  int lr = l & 15, lg = l >> 4;

  int sbi = span_begin[b * KK + i];
  for (int idx = t; idx < HH; idx += 256) left_s[idx] = left[(size_t)(b * KK + i) * HH + idx];
  for (int idx = t; idx < KP; idx += 256) bh_s[idx] = (idx < HH) ? b_h[idx] : 0.f;
  for (int idx = t; idx < 128; idx += 256) {
    int d = span_begin[b * KK + j0 + idx] - sbi; d = d < 0 ? -d : d;
    bins[idx] = d > NBINS - 1 ? NBINS - 1 : d;
    ssj_s[idx] = ss[b * KK + j0 + idx];
  }
  for (int idx = t; idx < 16 * 20; idx += 256) {
    int n = idx / 20, c = idx - n * 20;
    *(short8*)&wo_s[n][c * 8] = *(const short8*)(wo + n * KP + c * 8);
  }
  __syncthreads();

  // build h0 (pairs of columns; pad cols [150,168) zeroed)
  for (int idx = t; idx < 128 * 84; idx += 256) {
    int r = idx / 84, mp = idx - r * 84;
    int m = mp * 2;
    int v;
    if (mp < 75) {
      const float* rr = right + (size_t)(b * KK + j0 + r) * HH;
      float2 rv = *(const float2*)(rr + m);
      const float* de = demb + bins[r] * HH;
      float v0 = fmaxf(left_s[m]     + rv.x + de[m],     0.f);
      float v1 = fmaxf(left_s[m + 1] + rv.y + de[m + 1], 0.f);
      v = (int)(f2bfu(v0) | (f2bfu(v1) << 16));
    } else v = 0;
    ((int*)&h0[r][0])[mp] = v;
  }

  // GEMM1: wave w owns rows [w*32, w*32+32) as 2 row-tiles x 10 n-tiles
  f32x4 acc[2][10];
  #pragma unroll
  for (int rt = 0; rt < 2; ++rt)
    #pragma unroll
    for (int nt = 0; nt < 10; ++nt)
      acc[rt][nt] = (f32x4){0.f, 0.f, 0.f, 0.f};

  int rb = w * 32;
  for (int ks = 0; ks < 5; ++ks) {
    __syncthreads();
    for (int idx = t; idx < KP * 4; idx += 256) {
      int n = idx >> 2, c = idx & 3;
      *(short8*)&wt_s[n][c * 8] = *(const short8*)(wt + n * KP + ks * 32 + c * 8);
    }
    __syncthreads();
    short8 a0 = *(short8*)&h0[rb + lr][ks * 32 + lg * 8];
    short8 a1 = *(short8*)&h0[rb + 16 + lr][ks * 32 + lg * 8];
    #pragma unroll
    for (int nt = 0; nt < 10; ++nt) {
      short8 bf = *(short8*)&wt_s[nt * 16 + lr][lg * 8];
      acc[0][nt] = __builtin_amdgcn_mfma_f32_16x16x32_bf16(a0, bf, acc[0][nt], 0, 0, 0);
      acc[1][nt] = __builtin_amdgcn_mfma_f32_16x16x32_bf16(a1, bf, acc[1][nt], 0, 0, 0);
    }
  }

  __syncthreads();   // all GEMM1 LDS reads done
  // h1 = relu(acc + b_h) -> bf16 into h0 tile
  #pragma unroll
  for (int rt = 0; rt < 2; ++rt)
    #pragma unroll
    for (int nt = 0; nt < 10; ++nt) {
      int n = nt * 16 + lr;
      float bh = bh_s[n];
      #pragma unroll
      for (int q = 0; q < 4; ++q) {
        int row = rb + rt * 16 + lg * 4 + q;
        float hv = fmaxf(acc[rt][nt][q] + bh, 0.f);
        h0[row][n] = (short)f2bfu(hv);
      }
    }
  __syncthreads();

  // GEMM2: h1 @ wo  (N=16, labels in cols 0..10)
  f32x4 acc2[2] = {(f32x4){0.f,0.f,0.f,0.f}, (f32x4){0.f,0.f,0.f,0.f}};
  #pragma unroll
  for (int ks = 0; ks < 5; ++ks) {
    short8 bf = *(short8*)&wo_s[lr][ks * 32 + lg * 8];
    short8 a0 = *(short8*)&h0[rb + lr][ks * 32 + lg * 8];
    short8 a1 = *(short8*)&h0[rb + 16 + lr][ks * 32 + lg * 8];
    acc2[0] = __builtin_amdgcn_mfma_f32_16x16x32_bf16(a0, bf, acc2[0], 0, 0, 0);
    acc2[1] = __builtin_amdgcn_mfma_f32_16x16x32_bf16(a1, bf, acc2[1], 0, 0, 0);
  }

  // epilogue: stage [128][12] f32 in wt_s region, then coalesced store
  float ssi = ss[b * KK + i];
  float* out_s = (float*)&wt_s[0][0];
  float bo = (lr < LL) ? b_out[lr] : 0.f;
  #pragma unroll
  for (int rt = 0; rt < 2; ++rt)
    #pragma unroll
    for (int q = 0; q < 4; ++q) {
      int row = rb + rt * 16 + lg * 4 + q;
      if (lr < LL) out_s[row * 12 + lr] = acc2[rt][q] + bo + ssi + ssj_s[row];
    }
  __syncthreads();
  size_t base = ((size_t)(b * KK + i) * KK + j0) * LL;
  for (int idx = t; idx < 128 * LL; idx += 256) {
    int j = idx / LL, ll2 = idx - j * LL;
    rel[base + idx] = out_s[j * 12 + ll2];
  }
}

// ---------------- ctxt ----------------
__global__ __launch_bounds__(256) void k_ctxt(
    const float* __restrict__ upd, const float* __restrict__ rel,
    const float* __restrict__ mask, const float* __restrict__ a_w,
    const float* __restrict__ span_len, float* __restrict__ ctxt)
{
  int b = blockIdx.x / (KK / JT);
  int j0 = (blockIdx.x - b * (KK / JT)) * JT;
  int t = threadIdx.x;
  float aw[LL][3];
  #pragma unroll
  for (int l = 0; l < LL; ++l)
    #pragma unroll
    for (int c = 0; c < 3; ++c)
      aw[l][c] = a_w[l * DD + c * 256 + t];
  float acc[JT][3] = {};
  __shared__ float p[16][JT][LL + 1];
  for (int i0 = 0; i0 < KK; i0 += 16) {
    __syncthreads();
    for (int idx = t; idx < 16 * JT * LL; idx += 256) {
      int il = idx / (JT * LL);
      int r  = idx - il * (JT * LL);
      int jt = r / LL, l = r - jt * LL;
      size_t pij = ((size_t)(b * KK + i0 + il)) * KK + (j0 + jt);
      float mv = mask[pij];
      float v  = rel[pij * LL + l];
      p[il][jt][l] = fmaxf(v, 0.f) * mv;
    }
    __syncthreads();
    for (int il = 0; il < 16; ++il) {
      int i = i0 + il;
      size_t ub = ((size_t)(b * KK + i)) * DD;
      float u0 = upd[ub + t];
      float u1 = upd[ub + 256 + t];
      float u2 = upd[ub + 512 + t];
      #pragma unroll
      for (int jt = 0; jt < JT; ++jt) {
        float pa0 = 0.f, pa1 = 0.f, pa2 = 0.f;
        #pragma unroll
        for (int l = 0; l < LL; ++l) {
          float pv = p[il][jt][l];
          pa0 = fmaf(pv, aw[l][0], pa0);
          pa1 = fmaf(pv, aw[l][1], pa1);
          pa2 = fmaf(pv, aw[l][2], pa2);
        }
        acc[jt][0] = fmaf(u0, pa0, acc[jt][0]);
        acc[jt][1] = fmaf(u1, pa1, acc[jt][1]);
        acc[jt][2] = fmaf(u2, pa2, acc[jt][2]);
      }
    }
  }
  float inv = 1.f / span_len[b];
  #pragma unroll
  for (int jt = 0; jt < JT; ++jt) {
    size_t base = ((size_t)(b * KK + j0 + jt)) * DD;
    ctxt[base + t]       = acc[jt][0] * inv;
    ctxt[base + 256 + t] = acc[jt][1] * inv;
    ctxt[base + 512 + t] = acc[jt][2] * inv;
  }
}

// ---------------- gate + blend ----------------
__global__ __launch_bounds__(256) void k_gate(
    const float* __restrict__ upd, const float* __restrict__ ctxt,
    const float* __restrict__ gate_w, const float* __restrict__ gate_b,
    float* __restrict__ upd_out)
{
  const int RB = 8;
  int rb = blockIdx.x / 3;
  int cb = blockIdx.x - rb * 3;
  int row0 = rb * RB;
  int c = cb * 256 + threadIdx.x;
  float acc[RB] = {};
  #pragma unroll 4
  for (int m = 0; m < DD; ++m) {
    float w = gate_w[(size_t)m * DD + c];
    #pragma unroll
    for (int r = 0; r < RB; ++r)
      acc[r] = fmaf(upd[(size_t)(row0 + r) * DD + m], w, acc[r]);
  }
  #pragma unroll 4
  for (int m = 0; m < DD; ++m) {
    float w = gate_w[(size_t)(DD + m) * DD + c];
    #pragma unroll
    for (int r = 0; r < RB; ++r)
      acc[r] = fmaf(ctxt[(size_t)(row0 + r) * DD + m], w, acc[r]);
  }
  float gb = gate_b[c];
  #pragma unroll
  for (int r = 0; r < RB; ++r) {
    float x = acc[r] + gb;
    float g = 1.f / (1.f + expf(-x));
    float uv = upd[(size_t)(row0 + r) * DD + c];
    float cv = ctxt[(size_t)(row0 + r) * DD + c];
    upd_out[(size_t)(row0 + r) * DD + c] = g * uv + (1.f - g) * cv;
  }
}

// ---------------- scatter ----------------
__global__ void k_scatter(const float* __restrict__ upd,
                          const int* __restrict__ prune_idx,
                          const float* __restrict__ span_len,
                          float* __restrict__ out_all)
{
  int b = blockIdx.x / KK;
  int k = blockIdx.x - b * KK;
  if ((float)k < span_len[b]) {
    int dst = prune_idx[b * KK + k];
    const float4* src = (const float4*)(upd + ((size_t)(b * KK + k)) * DD);
    float4* d = (float4*)(out_all + ((size_t)b * NN + dst) * DD);
    for (int idx = threadIdx.x; idx < DD / 4; idx += blockDim.x) d[idx] = src[idx];
  }
}

extern "C" void kernel_launch(void* const* d_in, const int* in_sizes, int n_in,
                              void* d_out, int out_size, void* d_ws, size_t ws_size,
                              hipStream_t stream)
{
  (void)in_sizes; (void)n_in; (void)out_size; (void)ws_size;
  const float* all_span = (const float*)d_in[0];
  const float* upd_in   = (const float*)d_in[1];
  const float* mask     = (const float*)d_in[2];
  const float* span_len = (const float*)d_in[3];
  const int*   span_beg = (const int*)d_in[4];
  const int*   prune    = (const int*)d_in[6];
  const float* w_left   = (const float*)d_in[7];
  const float* b_left   = (const float*)d_in[8];
  const float* w_right  = (const float*)d_in[9];
  const float* b_right  = (const float*)d_in[10];
  const float* dist_emb = (const float*)d_in[11];
  const float* w_h      = (const float*)d_in[12];
  const float* b_h      = (const float*)d_in[13];
  const float* w_out    = (const float*)d_in[14];
  const float* b_out    = (const float*)d_in[15];
  const float* a_w      = (const float*)d_in[16];
  const float* gate_w   = (const float*)d_in[17];
  const float* gate_b   = (const float*)d_in[18];
  const float* pr_w     = (const float*)d_in[19];
  const float* pr_b     = (const float*)d_in[20];

  float* out_all = (float*)d_out;
  float* out_upd = out_all + (size_t)BB * NN * DD;
  float* out_rel = out_upd + (size_t)BB * KK * DD;

  float* ws     = (float*)d_ws;
  float* left   = ws;
  float* right  = left + (size_t)BB * KK * HH;
  float* ssv    = right + (size_t)BB * KK * HH;
  float* ctxt   = ssv + (size_t)BB * KK;
  float* upd_ws = ctxt + (size_t)BB * KK * DD;
  short* wt_bf  = (short*)(upd_ws + (size_t)BB * KK * DD);
  short* wo_bf  = wt_bf + KP * KP;

  hipMemcpyAsync(out_all, all_span, sizeof(float) * (size_t)BB * NN * DD,
                 hipMemcpyDeviceToDevice, stream);
  hipMemcpyAsync(out_upd, upd_in, sizeof(float) * (size_t)BB * KK * DD,
                 hipMemcpyDeviceToDevice, stream);
  k_prep<<<(KP * KP + 16 * KP + 255) / 256, 256, 0, stream>>>(w_h, w_out, wt_bf, wo_bf);

  k_proj<<<BB * KK / 2, 384, 0, stream>>>(out_upd, w_left, b_left, w_right, b_right,
                                          pr_w, pr_b, left, right, ssv);
  k_pair_mfma<<<BB * KK * 2, 256, 0, stream>>>(left, right, ssv, span_beg, dist_emb,
                                               wt_bf, wo_bf, b_h, b_out, out_rel);

  for (int p = 0; p < 2; ++p) {
    const float* cur = (p == 0) ? out_upd : upd_ws;
    float* nxt       = (p == 0) ? upd_ws  : out_upd;
    k_ctxt<<<BB * (KK / JT), 256, 0, stream>>>(cur, out_rel, mask, a_w, span_len, ctxt);
    k_gate<<<(BB * KK / 8) * 3, 256, 0, stream>>>(cur, ctxt, gate_w, gate_b, nxt);
    k_proj<<<BB * KK / 2, 384, 0, stream>>>(nxt, w_left, b_left, w_right, b_right,
                                            pr_w, pr_b, left, right, ssv);
    k_pair_mfma<<<BB * KK * 2, 256, 0, stream>>>(left, right, ssv, span_beg, dist_emb,
                                                 wt_bf, wo_bf, b_h, b_out, out_rel);
  }
  k_scatter<<<BB * KK, 192, 0, stream>>>(out_upd, prune, span_len, out_all);
}

// Round 3
// 507.497 us; speedup vs baseline: 2.7241x; 1.6381x over previous
//
#include <hip/hip_runtime.h>
#include <math.h>

#define BB 2
#define NN 2048
#define KK 256
#define DD 768
#define HH 150
#define LL 11
#define NBINS 10
#define JT 2

#define KP 160          // padded K/N for MFMA tiles
#define RP 168          // h0/h1/wo row stride in shorts (bank-conflict pad)
#define WP 40           // staged k-slice row stride in shorts

typedef __attribute__((ext_vector_type(8))) short short8;
typedef __attribute__((ext_vector_type(4))) float f32x4;

__device__ inline unsigned f2bfu(float x) {
  unsigned u = __float_as_uint(x);
  unsigned r = ((u >> 16) & 1u) + 0x7fffu;
  return (u + r) >> 16;
}

// ---------------- prep: bf16 zero-padded transposed pair weights ----------------
__global__ void k_prep(const float* __restrict__ w_h, const float* __restrict__ w_out,
                       short* __restrict__ wt, short* __restrict__ wo) {
  int idx = blockIdx.x * 256 + threadIdx.x;
  if (idx < KP * KP) {
    int n = idx / KP, k = idx - n * KP;
    float v = (n < HH && k < HH) ? w_h[k * HH + n] : 0.f;
    wt[idx] = (short)f2bfu(v);
  }
  int idx2 = idx - KP * KP;
  if (idx2 >= 0 && idx2 < 16 * KP) {
    int n = idx2 / KP, k = idx2 - n * KP;
    float v = (n < LL && k < HH) ? w_out[k * LL + n] : 0.f;
    wo[idx2] = (short)f2bfu(v);
  }
}

// ---------------- f32 -> bf16 convert ----------------
__global__ void k_cvt(const float* __restrict__ src, short* __restrict__ dst, int n) {
  int idx = blockIdx.x * 256 + threadIdx.x;
  if (idx < n) dst[idx] = (short)f2bfu(src[idx]);
}

// ---------------- tiled transpose gate_w [1536][768] -> gwt bf16 [768][1536] ----------------
__global__ __launch_bounds__(256) void k_tr_gw(const float* __restrict__ gate_w,
                                               short* __restrict__ gwt) {
  __shared__ float tile[32][33];
  int kt = blockIdx.x % 48, nt = blockIdx.x / 48;
  int m0 = kt * 32, n0 = nt * 32;
  int tx = threadIdx.x & 31, ty = threadIdx.x >> 5;
  #pragma unroll
  for (int r = 0; r < 4; ++r)
    tile[ty + r * 8][tx] = gate_w[(size_t)(m0 + ty + r * 8) * DD + n0 + tx];
  __syncthreads();
  #pragma unroll
  for (int r = 0; r < 4; ++r)
    gwt[(size_t)(n0 + ty + r * 8) * (2 * DD) + m0 + tx] = (short)f2bfu(tile[tx][ty + r * 8]);
}

// ---------------- tiled transpose w_left/w_right [768][150] -> wlrt bf16 [320][768] ----------------
__global__ __launch_bounds__(256) void k_tr_wlr(const float* __restrict__ w_left,
                                                const float* __restrict__ w_right,
                                                short* __restrict__ wlrt) {
  __shared__ float tile[32][33];
  int kt = blockIdx.x % 24, nt = blockIdx.x / 24;
  int k0 = kt * 32, n0 = nt * 32;
  const float* src = (n0 >= KP) ? w_right : w_left;
  int col0 = n0 - (n0 >= KP ? KP : 0);
  int tx = threadIdx.x & 31, ty = threadIdx.x >> 5;
  #pragma unroll
  for (int r = 0; r < 4; ++r) {
    int col = col0 + tx;
    tile[ty + r * 8][tx] = (col < HH) ? src[(size_t)(k0 + ty + r * 8) * HH + col] : 0.f;
  }
  __syncthreads();
  #pragma unroll
  for (int r = 0; r < 4; ++r)
    wlrt[(size_t)(n0 + ty + r * 8) * DD + k0 + tx] = (short)f2bfu(tile[tx][ty + r * 8]);
}

// ---------------- pruner scores ss = upd . pr_w + pr_b (f32) ----------------
__global__ __launch_bounds__(256) void k_ss(const float* __restrict__ upd,
                                            const float* __restrict__ pr_w,
                                            const float* __restrict__ pr_b,
                                            float* __restrict__ ss) {
  int row = blockIdx.x * 4 + (threadIdx.x >> 6);
  int l = threadIdx.x & 63;
  float s = 0.f;
  for (int d = l; d < DD; d += 64) s = fmaf(upd[(size_t)row * DD + d], pr_w[d], s);
  #pragma unroll
  for (int off = 32; off > 0; off >>= 1) s += __shfl_down(s, off);
  if (l == 0) ss[row] = s + pr_b[0];
}

// ---------------- proj via MFMA: left/right = upd @ w_{left,right} ----------------
// grid 16 = 8 row-blocks x 2 halves; 64 rows x 160 cols, K=768
__global__ __launch_bounds__(256) void k_proj_mfma(
    const short* __restrict__ updbf, const short* __restrict__ wlrt,
    const float* __restrict__ b_left, const float* __restrict__ b_right,
    float* __restrict__ left, float* __restrict__ right)
{
  int rbk = blockIdx.x >> 1, half = blockIdx.x & 1;
  int row0 = rbk * 64;
  const short* wsrc = wlrt + (size_t)half * KP * DD;
  __shared__ short As[64][WP];
  __shared__ short Bs[KP][WP];
  int t = threadIdx.x, l = t & 63, w = t >> 6, lr = l & 15, lg = l >> 4;
  int ar = t >> 2, ac = t & 3;
  int i1 = t + 256, i2 = t + 512;
  f32x4 acc[10];
  #pragma unroll
  for (int nt = 0; nt < 10; ++nt) acc[nt] = (f32x4){0.f, 0.f, 0.f, 0.f};

  short8 pa, pb0, pb1, pb2 = {};
  pa  = *(const short8*)(updbf + (size_t)(row0 + ar) * DD + ac * 8);
  pb0 = *(const short8*)(wsrc + (size_t)(t >> 2) * DD + (t & 3) * 8);
  pb1 = *(const short8*)(wsrc + (size_t)(i1 >> 2) * DD + (i1 & 3) * 8);
  if (i2 < 640) pb2 = *(const short8*)(wsrc + (size_t)(i2 >> 2) * DD + (i2 & 3) * 8);

  for (int ks = 0; ks < 24; ++ks) {
    __syncthreads();
    *(short8*)&As[ar][ac * 8] = pa;
    *(short8*)&Bs[t >> 2][(t & 3) * 8] = pb0;
    *(short8*)&Bs[i1 >> 2][(i1 & 3) * 8] = pb1;
    if (i2 < 640) *(short8*)&Bs[i2 >> 2][(i2 & 3) * 8] = pb2;
    __syncthreads();
    if (ks + 1 < 24) {
      int k0 = (ks + 1) * 32;
      pa  = *(const short8*)(updbf + (size_t)(row0 + ar) * DD + k0 + ac * 8);
      pb0 = *(const short8*)(wsrc + (size_t)(t >> 2) * DD + k0 + (t & 3) * 8);
      pb1 = *(const short8*)(wsrc + (size_t)(i1 >> 2) * DD + k0 + (i1 & 3) * 8);
      if (i2 < 640) pb2 = *(const short8*)(wsrc + (size_t)(i2 >> 2) * DD + k0 + (i2 & 3) * 8);
    }
    short8 a = *(short8*)&As[w * 16 + lr][lg * 8];
    #pragma unroll
    for (int nt = 0; nt < 10; ++nt) {
      short8 b = *(short8*)&Bs[nt * 16 + lr][lg * 8];
      acc[nt] = __builtin_amdgcn_mfma_f32_16x16x32_bf16(a, b, acc[nt], 0, 0, 0);
    }
  }
  const float* bias = half ? b_right : b_left;
  float* dst = half ? right : left;
  int rowb = row0 + w * 16 + lg * 4;
  #pragma unroll
  for (int nt = 0; nt < 10; ++nt) {
    int col = nt * 16 + lr;
    if (col < HH) {
      float bv = bias[col];
      #pragma unroll
      for (int q = 0; q < 4; ++q)
        dst[(size_t)(rowb + q) * HH + col] = acc[nt][q] + bv;
    }
  }
}

// ---------------- pair scores via MFMA ----------------
__global__ __launch_bounds__(256) void k_pair_mfma(
    const float* __restrict__ left, const float* __restrict__ right,
    const float* __restrict__ ss, const int* __restrict__ span_begin,
    const float* __restrict__ demb,
    const short* __restrict__ wt, const short* __restrict__ wo,
    const float* __restrict__ b_h, const float* __restrict__ b_out,
    float* __restrict__ rel)
{
  int b  = blockIdx.x >> 9;
  int r2 = blockIdx.x & 511;
  int i  = r2 >> 1;
  int j0 = (r2 & 1) * 128;

  __shared__ short h0[128][RP];
  __shared__ short wt_s[KP][WP];
  __shared__ short wo_s[16][RP];
  __shared__ float left_s[152];
  __shared__ float bh_s[KP];
  __shared__ float ssj_s[128];
  __shared__ int   bins[128];

  int t = threadIdx.x;
  int l = t & 63, w = t >> 6;
  int lr = l & 15, lg = l >> 4;

  int sbi = span_begin[b * KK + i];
  for (int idx = t; idx < HH; idx += 256) left_s[idx] = left[(size_t)(b * KK + i) * HH + idx];
  for (int idx = t; idx < KP; idx += 256) bh_s[idx] = (idx < HH) ? b_h[idx] : 0.f;
  for (int idx = t; idx < 128; idx += 256) {
    int d = span_begin[b * KK + j0 + idx] - sbi; d = d < 0 ? -d : d;
    bins[idx] = d > NBINS - 1 ? NBINS - 1 : d;
    ssj_s[idx] = ss[b * KK + j0 + idx];
  }
  for (int idx = t; idx < 16 * 20; idx += 256) {
    int n = idx / 20, c = idx - n * 20;
    *(short8*)&wo_s[n][c * 8] = *(const short8*)(wo + n * KP + c * 8);
  }
  __syncthreads();

  for (int idx = t; idx < 128 * 84; idx += 256) {
    int r = idx / 84, mp = idx - r * 84;
    int m = mp * 2;
    int v;
    if (mp < 75) {
      const float* rr = right + (size_t)(b * KK + j0 + r) * HH;
      float2 rv = *(const float2*)(rr + m);
      const float* de = demb + bins[r] * HH;
      float v0 = fmaxf(left_s[m]     + rv.x + de[m],     0.f);
      float v1 = fmaxf(left_s[m + 1] + rv.y + de[m + 1], 0.f);
      v = (int)(f2bfu(v0) | (f2bfu(v1) << 16));
    } else v = 0;
    ((int*)&h0[r][0])[mp] = v;
  }

  f32x4 acc[2][10];
  #pragma unroll
  for (int rt = 0; rt < 2; ++rt)
    #pragma unroll
    for (int nt = 0; nt < 10; ++nt)
      acc[rt][nt] = (f32x4){0.f, 0.f, 0.f, 0.f};

  int rb = w * 32;
  for (int ks = 0; ks < 5; ++ks) {
    __syncthreads();
    for (int idx = t; idx < KP * 4; idx += 256) {
      int n = idx >> 2, c = idx & 3;
      *(short8*)&wt_s[n][c * 8] = *(const short8*)(wt + n * KP + ks * 32 + c * 8);
    }
    __syncthreads();
    short8 a0 = *(short8*)&h0[rb + lr][ks * 32 + lg * 8];
    short8 a1 = *(short8*)&h0[rb + 16 + lr][ks * 32 + lg * 8];
    #pragma unroll
    for (int nt = 0; nt < 10; ++nt) {
      short8 bf = *(short8*)&wt_s[nt * 16 + lr][lg * 8];
      acc[0][nt] = __builtin_amdgcn_mfma_f32_16x16x32_bf16(a0, bf, acc[0][nt], 0, 0, 0);
      acc[1][nt] = __builtin_amdgcn_mfma_f32_16x16x32_bf16(a1, bf, acc[1][nt], 0, 0, 0);
    }
  }

  __syncthreads();
  #pragma unroll
  for (int rt = 0; rt < 2; ++rt)
    #pragma unroll
    for (int nt = 0; nt < 10; ++nt) {
      int n = nt * 16 + lr;
      float bh = bh_s[n];
      #pragma unroll
      for (int q = 0; q < 4; ++q) {
        int row = rb + rt * 16 + lg * 4 + q;
        float hv = fmaxf(acc[rt][nt][q] + bh, 0.f);
        h0[row][n] = (short)f2bfu(hv);
      }
    }
  __syncthreads();

  f32x4 acc2[2] = {(f32x4){0.f,0.f,0.f,0.f}, (f32x4){0.f,0.f,0.f,0.f}};
  #pragma unroll
  for (int ks = 0; ks < 5; ++ks) {
    short8 bf = *(short8*)&wo_s[lr][ks * 32 + lg * 8];
    short8 a0 = *(short8*)&h0[rb + lr][ks * 32 + lg * 8];
    short8 a1 = *(short8*)&h0[rb + 16 + lr][ks * 32 + lg * 8];
    acc2[0] = __builtin_amdgcn_mfma_f32_16x16x32_bf16(a0, bf, acc2[0], 0, 0, 0);
    acc2[1] = __builtin_amdgcn_mfma_f32_16x16x32_bf16(a1, bf, acc2[1], 0, 0, 0);
  }

  float ssi = ss[b * KK + i];
  float* out_s = (float*)&wt_s[0][0];
  float bo = (lr < LL) ? b_out[lr] : 0.f;
  #pragma unroll
  for (int rt = 0; rt < 2; ++rt)
    #pragma unroll
    for (int q = 0; q < 4; ++q) {
      int row = rb + rt * 16 + lg * 4 + q;
      if (lr < LL) out_s[row * 12 + lr] = acc2[rt][q] + bo + ssi + ssj_s[row];
    }
  __syncthreads();
  size_t base = ((size_t)(b * KK + i) * KK + j0) * LL;
  for (int idx = t; idx < 128 * LL; idx += 256) {
    int j = idx / LL, ll2 = idx - j * LL;
    rel[base + idx] = out_s[j * 12 + ll2];
  }
}

// ---------------- ctxt (f32 + bf16 mirror) ----------------
__global__ __launch_bounds__(256) void k_ctxt(
    const float* __restrict__ upd, const float* __restrict__ rel,
    const float* __restrict__ mask, const float* __restrict__ a_w,
    const float* __restrict__ span_len, float* __restrict__ ctxt,
    short* __restrict__ ctxbf)
{
  int b = blockIdx.x / (KK / JT);
  int j0 = (blockIdx.x - b * (KK / JT)) * JT;
  int t = threadIdx.x;
  float aw[LL][3];
  #pragma unroll
  for (int l = 0; l < LL; ++l)
    #pragma unroll
    for (int c = 0; c < 3; ++c)
      aw[l][c] = a_w[l * DD + c * 256 + t];
  float acc[JT][3] = {};
  __shared__ float p[16][JT][LL + 1];
  for (int i0 = 0; i0 < KK; i0 += 16) {
    __syncthreads();
    for (int idx = t; idx < 16 * JT * LL; idx += 256) {
      int il = idx / (JT * LL);
      int r  = idx - il * (JT * LL);
      int jt = r / LL, l = r - jt * LL;
      size_t pij = ((size_t)(b * KK + i0 + il)) * KK + (j0 + jt);
      float mv = mask[pij];
      float v  = rel[pij * LL + l];
      p[il][jt][l] = fmaxf(v, 0.f) * mv;
    }
    __syncthreads();
    for (int il = 0; il < 16; ++il) {
      int i = i0 + il;
      size_t ub = ((size_t)(b * KK + i)) * DD;
      float u0 = upd[ub + t];
      float u1 = upd[ub + 256 + t];
      float u2 = upd[ub + 512 + t];
      #pragma unroll
      for (int jt = 0; jt < JT; ++jt) {
        float pa0 = 0.f, pa1 = 0.f, pa2 = 0.f;
        #pragma unroll
        for (int l = 0; l < LL; ++l) {
          float pv = p[il][jt][l];
          pa0 = fmaf(pv, aw[l][0], pa0);
          pa1 = fmaf(pv, aw[l][1], pa1);
          pa2 = fmaf(pv, aw[l][2], pa2);
        }
        acc[jt][0] = fmaf(u0, pa0, acc[jt][0]);
        acc[jt][1] = fmaf(u1, pa1, acc[jt][1]);
        acc[jt][2] = fmaf(u2, pa2, acc[jt][2]);
      }
    }
  }
  float inv = 1.f / span_len[b];
  #pragma unroll
  for (int jt = 0; jt < JT; ++jt) {
    size_t base = ((size_t)(b * KK + j0 + jt)) * DD;
    #pragma unroll
    for (int c = 0; c < 3; ++c) {
      float v = acc[jt][c] * inv;
      ctxt[base + c * 256 + t] = v;
      ctxbf[base + c * 256 + t] = (short)f2bfu(v);
    }
  }
}

// ---------------- gate via MFMA: 64x64 tiles, K=1536 ----------------
__global__ __launch_bounds__(256) void k_gate_mfma(
    const short* __restrict__ updbf, const short* __restrict__ ctxbf,
    const short* __restrict__ gwt, const float* __restrict__ gate_b,
    const float* __restrict__ ctxt, float* __restrict__ upd,
    short* __restrict__ nxtbf)
{
  int rb = blockIdx.x / 12, cb = blockIdx.x - rb * 12;
  int row0 = rb * 64, col0 = cb * 64;
  __shared__ short As[64][WP];
  __shared__ short Bs[64][WP];
  int t = threadIdx.x, l = t & 63, w = t >> 6, lr = l & 15, lg = l >> 4;
  int r = t >> 2, c = t & 3;
  size_t arow = (size_t)(row0 + r) * DD;
  size_t brow = (size_t)(col0 + r) * (2 * DD);

  f32x4 acc[4];
  #pragma unroll
  for (int nt = 0; nt < 4; ++nt) acc[nt] = (f32x4){0.f, 0.f, 0.f, 0.f};

  short8 pa = *(const short8*)(updbf + arow + c * 8);
  short8 pb = *(const short8*)(gwt + brow + c * 8);
  for (int ks = 0; ks < 48; ++ks) {
    __syncthreads();
    *(short8*)&As[r][c * 8] = pa;
    *(short8*)&Bs[r][c * 8] = pb;
    __syncthreads();
    if (ks + 1 < 48) {
      int k0 = (ks + 1) * 32;
      const short* asrc = (k0 < DD) ? (updbf + arow + k0) : (ctxbf + arow + k0 - DD);
      pa = *(const short8*)(asrc + c * 8);
      pb = *(const short8*)(gwt + brow + k0 + c * 8);
    }
    short8 a = *(short8*)&As[w * 16 + lr][lg * 8];
    #pragma unroll
    for (int nt = 0; nt < 4; ++nt) {
      short8 b = *(short8*)&Bs[nt * 16 + lr][lg * 8];
      acc[nt] = __builtin_amdgcn_mfma_f32_16x16x32_bf16(a, b, acc[nt], 0, 0, 0);
    }
  }
  int rowb = row0 + w * 16 + lg * 4;
  #pragma unroll
  for (int nt = 0; nt < 4; ++nt) {
    int col = col0 + nt * 16 + lr;
    float gb = gate_b[col];
    #pragma unroll
    for (int q = 0; q < 4; ++q) {
      size_t off = (size_t)(rowb + q) * DD + col;
      float x = acc[nt][q] + gb;
      float g = 1.f / (1.f + expf(-x));
      float o = g * upd[off] + (1.f - g) * ctxt[off];
      upd[off] = o;
      nxtbf[off] = (short)f2bfu(o);
    }
  }
}

// ---------------- scatter ----------------
__global__ void k_scatter(const float* __restrict__ upd,
                          const int* __restrict__ prune_idx,
                          const float* __restrict__ span_len,
                          float* __restrict__ out_all)
{
  int b = blockIdx.x / KK;
  int k = blockIdx.x - b * KK;
  if ((float)k < span_len[b]) {
    int dst = prune_idx[b * KK + k];
    const float4* src = (const float4*)(upd + ((size_t)(b * KK + k)) * DD);
    float4* d = (float4*)(out_all + ((size_t)b * NN + dst) * DD);
    for (int idx = threadIdx.x; idx < DD / 4; idx += blockDim.x) d[idx] = src[idx];
  }
}

extern "C" void kernel_launch(void* const* d_in, const int* in_sizes, int n_in,
                              void* d_out, int out_size, void* d_ws, size_t ws_size,
                              hipStream_t stream)
{
  (void)in_sizes; (void)n_in; (void)out_size; (void)ws_size;
  const float* all_span = (const float*)d_in[0];
  const float* upd_in   = (const float*)d_in[1];
  const float* mask     = (const float*)d_in[2];
  const float* span_len = (const float*)d_in[3];
  const int*   span_beg = (const int*)d_in[4];
  const int*   prune    = (const int*)d_in[6];
  const float* w_left   = (const float*)d_in[7];
  const float* b_left   = (const float*)d_in[8];
  const float* w_right  = (const float*)d_in[9];
  const float* b_right  = (const float*)d_in[10];
  const float* dist_emb = (const float*)d_in[11];
  const float* w_h      = (const float*)d_in[12];
  const float* b_h      = (const float*)d_in[13];
  const float* w_out    = (const float*)d_in[14];
  const float* b_out    = (const float*)d_in[15];
  const float* a_w      = (const float*)d_in[16];
  const float* gate_w   = (const float*)d_in[17];
  const float* gate_b   = (const float*)d_in[18];
  const float* pr_w     = (const float*)d_in[19];
  const float* pr_b     = (const float*)d_in[20];

  float* out_all = (float*)d_out;
  float* out_upd = out_all + (size_t)BB * NN * DD;
  float* out_rel = out_upd + (size_t)BB * KK * DD;

  float* ws     = (float*)d_ws;
  float* left   = ws;                                   // 512*150
  float* right  = left + (size_t)BB * KK * HH;          // 512*150
  float* ssv    = right + (size_t)BB * KK * HH;         // 512
  float* ctxt   = ssv + (size_t)BB * KK;                // 512*768
  short* wt_bf  = (short*)(ctxt + (size_t)BB * KK * DD);// 160*160
  short* wo_bf  = wt_bf + KP * KP;                      // 16*160
  short* updbf0 = wo_bf + 16 * KP;                      // 512*768
  short* updbf1 = updbf0 + (size_t)BB * KK * DD;
  short* ctxbf  = updbf1 + (size_t)BB * KK * DD;
  short* gwt    = ctxbf + (size_t)BB * KK * DD;         // 768*1536
  short* wlrt   = gwt + (size_t)DD * 2 * DD;            // 320*768

  const int nupd = BB * KK * DD;

  hipMemcpyAsync(out_all, all_span, sizeof(float) * (size_t)BB * NN * DD,
                 hipMemcpyDeviceToDevice, stream);
  hipMemcpyAsync(out_upd, upd_in, sizeof(float) * (size_t)BB * KK * DD,
                 hipMemcpyDeviceToDevice, stream);
  k_prep<<<(KP * KP + 16 * KP + 255) / 256, 256, 0, stream>>>(w_h, w_out, wt_bf, wo_bf);
  k_cvt<<<(nupd + 255) / 256, 256, 0, stream>>>(upd_in, updbf0, nupd);
  k_tr_gw<<<48 * 24, 256, 0, stream>>>(gate_w, gwt);
  k_tr_wlr<<<24 * 10, 256, 0, stream>>>(w_left, w_right, wlrt);

  k_proj_mfma<<<16, 256, 0, stream>>>(updbf0, wlrt, b_left, b_right, left, right);
  k_ss<<<BB * KK / 4, 256, 0, stream>>>(out_upd, pr_w, pr_b, ssv);
  k_pair_mfma<<<BB * KK * 2, 256, 0, stream>>>(left, right, ssv, span_beg, dist_emb,
                                               wt_bf, wo_bf, b_h, b_out, out_rel);

  for (int p = 0; p < 2; ++p) {
    short* cur_bf = (p == 0) ? updbf0 : updbf1;
    short* nxt_bf = (p == 0) ? updbf1 : updbf0;
    k_ctxt<<<BB * (KK / JT), 256, 0, stream>>>(out_upd, out_rel, mask, a_w, span_len,
                                               ctxt, ctxbf);
    k_gate_mfma<<<8 * 12, 256, 0, stream>>>(cur_bf, ctxbf, gwt, gate_b, ctxt,
                                            out_upd, nxt_bf);
    k_proj_mfma<<<16, 256, 0, stream>>>(nxt_bf, wlrt, b_left, b_right, left, right);
    k_ss<<<BB * KK / 4, 256, 0, stream>>>(out_upd, pr_w, pr_b, ssv);
    k_pair_mfma<<<BB * KK * 2, 256, 0, stream>>>(left, right, ssv, span_beg, dist_emb,
                                                 wt_bf, wo_bf, b_h, b_out, out_rel);
  }
  k_scatter<<<BB * KK, 192, 0, stream>>>(out_upd, prune, span_len, out_all);
}

// Round 4
// 359.667 us; speedup vs baseline: 3.8438x; 1.4110x over previous
//
#include <hip/hip_runtime.h>
#include <math.h>

#define BB 2
#define NN 2048
#define KK 256
#define DD 768
#define HH 150
#define LL 11
#define NBINS 10

#define KP 160          // padded K/N for MFMA tiles
#define RP 168          // h0/h1/wo row stride in shorts (bank-conflict pad)
#define WP 40           // staged k-slice row stride in shorts
#define BPAD 264        // 256-i row stride in shorts (ctxt staging)

typedef __attribute__((ext_vector_type(8))) short short8;
typedef __attribute__((ext_vector_type(4))) float f32x4;

__device__ inline unsigned f2bfu(float x) {
  unsigned u = __float_as_uint(x);
  unsigned r = ((u >> 16) & 1u) + 0x7fffu;
  return (u + r) >> 16;
}

// ---------------- prep: bf16 zero-padded transposed pair weights ----------------
__global__ void k_prep(const float* __restrict__ w_h, const float* __restrict__ w_out,
                       short* __restrict__ wt, short* __restrict__ wo) {
  int idx = blockIdx.x * 256 + threadIdx.x;
  if (idx < KP * KP) {
    int n = idx / KP, k = idx - n * KP;
    float v = (n < HH && k < HH) ? w_h[k * HH + n] : 0.f;
    wt[idx] = (short)f2bfu(v);
  }
  int idx2 = idx - KP * KP;
  if (idx2 >= 0 && idx2 < 16 * KP) {
    int n = idx2 / KP, k = idx2 - n * KP;
    float v = (n < LL && k < HH) ? w_out[k * LL + n] : 0.f;
    wo[idx2] = (short)f2bfu(v);
  }
}

// ---------------- f32 -> bf16 convert ----------------
__global__ void k_cvt(const float* __restrict__ src, short* __restrict__ dst, int n) {
  int idx = blockIdx.x * 256 + threadIdx.x;
  if (idx < n) dst[idx] = (short)f2bfu(src[idx]);
}

// ---------------- tiled transpose gate_w [1536][768] -> gwt bf16 [768][1536] ----------------
__global__ __launch_bounds__(256) void k_tr_gw(const float* __restrict__ gate_w,
                                               short* __restrict__ gwt) {
  __shared__ float tile[32][33];
  int kt = blockIdx.x % 48, nt = blockIdx.x / 48;
  int m0 = kt * 32, n0 = nt * 32;
  int tx = threadIdx.x & 31, ty = threadIdx.x >> 5;
  #pragma unroll
  for (int r = 0; r < 4; ++r)
    tile[ty + r * 8][tx] = gate_w[(size_t)(m0 + ty + r * 8) * DD + n0 + tx];
  __syncthreads();
  #pragma unroll
  for (int r = 0; r < 4; ++r)
    gwt[(size_t)(n0 + ty + r * 8) * (2 * DD) + m0 + tx] = (short)f2bfu(tile[tx][ty + r * 8]);
}

// ---------------- tiled transpose w_left/w_right [768][150] -> wlrt bf16 [320][768] ----------------
__global__ __launch_bounds__(256) void k_tr_wlr(const float* __restrict__ w_left,
                                                const float* __restrict__ w_right,
                                                short* __restrict__ wlrt) {
  __shared__ float tile[32][33];
  int kt = blockIdx.x % 24, nt = blockIdx.x / 24;
  int k0 = kt * 32, n0 = nt * 32;
  const float* src = (n0 >= KP) ? w_right : w_left;
  int col0 = n0 - (n0 >= KP ? KP : 0);
  int tx = threadIdx.x & 31, ty = threadIdx.x >> 5;
  #pragma unroll
  for (int r = 0; r < 4; ++r) {
    int col = col0 + tx;
    tile[ty + r * 8][tx] = (col < HH) ? src[(size_t)(k0 + ty + r * 8) * HH + col] : 0.f;
  }
  __syncthreads();
  #pragma unroll
  for (int r = 0; r < 4; ++r)
    wlrt[(size_t)(n0 + ty + r * 8) * DD + k0 + tx] = (short)f2bfu(tile[tx][ty + r * 8]);
}

// ---------------- tiled transpose upd f32 [B][256][768] -> updT bf16 [B][768][256] ----------------
__global__ __launch_bounds__(256) void k_tr_upd(const float* __restrict__ upd,
                                                short* __restrict__ updT) {
  __shared__ float tile[32][33];
  int bidx = blockIdx.x;              // B * 8 * 24
  int b = bidx / 192;
  int r = bidx - b * 192;
  int it = r & 7, dt = r >> 3;
  int i0 = it * 32, d0 = dt * 32;
  int tx = threadIdx.x & 31, ty = threadIdx.x >> 5;
  #pragma unroll
  for (int rr = 0; rr < 4; ++rr)
    tile[ty + rr * 8][tx] = upd[(size_t)(b * KK + i0 + ty + rr * 8) * DD + d0 + tx];
  __syncthreads();
  #pragma unroll
  for (int rr = 0; rr < 4; ++rr)
    updT[(size_t)(b * DD + d0 + ty + rr * 8) * KK + i0 + tx] = (short)f2bfu(tile[tx][ty + rr * 8]);
}

// ---------------- probs transpose: rel [b][i][j][l] -> probsT bf16 [b][l][j][i] ----------------
__global__ __launch_bounds__(256) void k_ptr(const float* __restrict__ rel,
                                             const float* __restrict__ mask,
                                             short* __restrict__ probsT) {
  __shared__ float tile[32][353];
  __shared__ float maskS[32][32];
  int bidx = blockIdx.x;              // B*8*8
  int b = bidx >> 6;
  int r = bidx & 63;
  int it = r >> 3, jt = r & 7;
  int i0 = it * 32, j0 = jt * 32;
  int t = threadIdx.x;
  for (int idx = t; idx < 32 * 352; idx += 256) {
    int ii = idx / 352, c = idx - ii * 352;
    tile[ii][c] = rel[(((size_t)(b * KK + i0 + ii)) * KK + j0) * LL + c];
  }
  for (int idx = t; idx < 1024; idx += 256) {
    int ii = idx >> 5, jj = idx & 31;
    maskS[ii][jj] = mask[((size_t)(b * KK + i0 + ii)) * KK + j0 + jj];
  }
  __syncthreads();
  for (int idx = t; idx < LL * 1024; idx += 256) {
    int l = idx >> 10;
    int rem = idx & 1023;
    int jj = rem >> 5, ii = rem & 31;
    float v = fmaxf(tile[ii][jj * LL + l], 0.f) * maskS[ii][jj];
    probsT[(((size_t)(b * LL + l)) * KK + j0 + jj) * KK + i0 + ii] = (short)f2bfu(v);
  }
}

// ---------------- pruner scores ss = upd . pr_w + pr_b (f32) ----------------
__global__ __launch_bounds__(256) void k_ss(const float* __restrict__ upd,
                                            const float* __restrict__ pr_w,
                                            const float* __restrict__ pr_b,
                                            float* __restrict__ ss) {
  int row = blockIdx.x * 4 + (threadIdx.x >> 6);
  int l = threadIdx.x & 63;
  float s = 0.f;
  for (int d = l; d < DD; d += 64) s = fmaf(upd[(size_t)row * DD + d], pr_w[d], s);
  #pragma unroll
  for (int off = 32; off > 0; off >>= 1) s += __shfl_down(s, off);
  if (l == 0) ss[row] = s + pr_b[0];
}

// ---------------- proj via MFMA ----------------
__global__ __launch_bounds__(256) void k_proj_mfma(
    const short* __restrict__ updbf, const short* __restrict__ wlrt,
    const float* __restrict__ b_left, const float* __restrict__ b_right,
    float* __restrict__ left, float* __restrict__ right)
{
  int rbk = blockIdx.x >> 1, half = blockIdx.x & 1;
  int row0 = rbk * 64;
  const short* wsrc = wlrt + (size_t)half * KP * DD;
  __shared__ short As[64][WP];
  __shared__ short Bs[KP][WP];
  int t = threadIdx.x, l = t & 63, w = t >> 6, lr = l & 15, lg = l >> 4;
  int ar = t >> 2, ac = t & 3;
  int i1 = t + 256, i2 = t + 512;
  f32x4 acc[10];
  #pragma unroll
  for (int nt = 0; nt < 10; ++nt) acc[nt] = (f32x4){0.f, 0.f, 0.f, 0.f};

  short8 pa, pb0, pb1, pb2 = {};
  pa  = *(const short8*)(updbf + (size_t)(row0 + ar) * DD + ac * 8);
  pb0 = *(const short8*)(wsrc + (size_t)(t >> 2) * DD + (t & 3) * 8);
  pb1 = *(const short8*)(wsrc + (size_t)(i1 >> 2) * DD + (i1 & 3) * 8);
  if (i2 < 640) pb2 = *(const short8*)(wsrc + (size_t)(i2 >> 2) * DD + (i2 & 3) * 8);

  for (int ks = 0; ks < 24; ++ks) {
    __syncthreads();
    *(short8*)&As[ar][ac * 8] = pa;
    *(short8*)&Bs[t >> 2][(t & 3) * 8] = pb0;
    *(short8*)&Bs[i1 >> 2][(i1 & 3) * 8] = pb1;
    if (i2 < 640) *(short8*)&Bs[i2 >> 2][(i2 & 3) * 8] = pb2;
    __syncthreads();
    if (ks + 1 < 24) {
      int k0 = (ks + 1) * 32;
      pa  = *(const short8*)(updbf + (size_t)(row0 + ar) * DD + k0 + ac * 8);
      pb0 = *(const short8*)(wsrc + (size_t)(t >> 2) * DD + k0 + (t & 3) * 8);
      pb1 = *(const short8*)(wsrc + (size_t)(i1 >> 2) * DD + k0 + (i1 & 3) * 8);
      if (i2 < 640) pb2 = *(const short8*)(wsrc + (size_t)(i2 >> 2) * DD + k0 + (i2 & 3) * 8);
    }
    short8 a = *(short8*)&As[w * 16 + lr][lg * 8];
    #pragma unroll
    for (int nt = 0; nt < 10; ++nt) {
      short8 b = *(short8*)&Bs[nt * 16 + lr][lg * 8];
      acc[nt] = __builtin_amdgcn_mfma_f32_16x16x32_bf16(a, b, acc[nt], 0, 0, 0);
    }
  }
  const float* bias = half ? b_right : b_left;
  float* dst = half ? right : left;
  int rowb = row0 + w * 16 + lg * 4;
  #pragma unroll
  for (int nt = 0; nt < 10; ++nt) {
    int col = nt * 16 + lr;
    if (col < HH) {
      float bv = bias[col];
      #pragma unroll
      for (int q = 0; q < 4; ++q)
        dst[(size_t)(rowb + q) * HH + col] = acc[nt][q] + bv;
    }
  }
}

// ---------------- pair scores via MFMA ----------------
__global__ __launch_bounds__(256) void k_pair_mfma(
    const float* __restrict__ left, const float* __restrict__ right,
    const float* __restrict__ ss, const int* __restrict__ span_begin,
    const float* __restrict__ demb,
    const short* __restrict__ wt, const short* __restrict__ wo,
    const float* __restrict__ b_h, const float* __restrict__ b_out,
    float* __restrict__ rel)
{
  int b  = blockIdx.x >> 9;
  int r2 = blockIdx.x & 511;
  int i  = r2 >> 1;
  int j0 = (r2 & 1) * 128;

  __shared__ short h0[128][RP];
  __shared__ short wt_s[KP][WP];
  __shared__ short wo_s[16][RP];
  __shared__ float left_s[152];
  __shared__ float bh_s[KP];
  __shared__ float ssj_s[128];
  __shared__ int   bins[128];

  int t = threadIdx.x;
  int l = t & 63, w = t >> 6;
  int lr = l & 15, lg = l >> 4;

  int sbi = span_begin[b * KK + i];
  for (int idx = t; idx < HH; idx += 256) left_s[idx] = left[(size_t)(b * KK + i) * HH + idx];
  for (int idx = t; idx < KP; idx += 256) bh_s[idx] = (idx < HH) ? b_h[idx] : 0.f;
  for (int idx = t; idx < 128; idx += 256) {
    int d = span_begin[b * KK + j0 + idx] - sbi; d = d < 0 ? -d : d;
    bins[idx] = d > NBINS - 1 ? NBINS - 1 : d;
    ssj_s[idx] = ss[b * KK + j0 + idx];
  }
  for (int idx = t; idx < 16 * 20; idx += 256) {
    int n = idx / 20, c = idx - n * 20;
    *(short8*)&wo_s[n][c * 8] = *(const short8*)(wo + n * KP + c * 8);
  }
  __syncthreads();

  for (int idx = t; idx < 128 * 84; idx += 256) {
    int r = idx / 84, mp = idx - r * 84;
    int m = mp * 2;
    int v;
    if (mp < 75) {
      const float* rr = right + (size_t)(b * KK + j0 + r) * HH;
      float2 rv = *(const float2*)(rr + m);
      const float* de = demb + bins[r] * HH;
      float v0 = fmaxf(left_s[m]     + rv.x + de[m],     0.f);
      float v1 = fmaxf(left_s[m + 1] + rv.y + de[m + 1], 0.f);
      v = (int)(f2bfu(v0) | (f2bfu(v1) << 16));
    } else v = 0;
    ((int*)&h0[r][0])[mp] = v;
  }

  f32x4 acc[2][10];
  #pragma unroll
  for (int rt = 0; rt < 2; ++rt)
    #pragma unroll
    for (int nt = 0; nt < 10; ++nt)
      acc[rt][nt] = (f32x4){0.f, 0.f, 0.f, 0.f};

  int rb = w * 32;
  for (int ks = 0; ks < 5; ++ks) {
    __syncthreads();
    for (int idx = t; idx < KP * 4; idx += 256) {
      int n = idx >> 2, c = idx & 3;
      *(short8*)&wt_s[n][c * 8] = *(const short8*)(wt + n * KP + ks * 32 + c * 8);
    }
    __syncthreads();
    short8 a0 = *(short8*)&h0[rb + lr][ks * 32 + lg * 8];
    short8 a1 = *(short8*)&h0[rb + 16 + lr][ks * 32 + lg * 8];
    #pragma unroll
    for (int nt = 0; nt < 10; ++nt) {
      short8 bf = *(short8*)&wt_s[nt * 16 + lr][lg * 8];
      acc[0][nt] = __builtin_amdgcn_mfma_f32_16x16x32_bf16(a0, bf, acc[0][nt], 0, 0, 0);
      acc[1][nt] = __builtin_amdgcn_mfma_f32_16x16x32_bf16(a1, bf, acc[1][nt], 0, 0, 0);
    }
  }

  __syncthreads();
  #pragma unroll
  for (int rt = 0; rt < 2; ++rt)
    #pragma unroll
    for (int nt = 0; nt < 10; ++nt) {
      int n = nt * 16 + lr;
      float bh = bh_s[n];
      #pragma unroll
      for (int q = 0; q < 4; ++q) {
        int row = rb + rt * 16 + lg * 4 + q;
        float hv = fmaxf(acc[rt][nt][q] + bh, 0.f);
        h0[row][n] = (short)f2bfu(hv);
      }
    }
  __syncthreads();

  f32x4 acc2[2] = {(f32x4){0.f,0.f,0.f,0.f}, (f32x4){0.f,0.f,0.f,0.f}};
  #pragma unroll
  for (int ks = 0; ks < 5; ++ks) {
    short8 bf = *(short8*)&wo_s[lr][ks * 32 + lg * 8];
    short8 a0 = *(short8*)&h0[rb + lr][ks * 32 + lg * 8];
    short8 a1 = *(short8*)&h0[rb + 16 + lr][ks * 32 + lg * 8];
    acc2[0] = __builtin_amdgcn_mfma_f32_16x16x32_bf16(a0, bf, acc2[0], 0, 0, 0);
    acc2[1] = __builtin_amdgcn_mfma_f32_16x16x32_bf16(a1, bf, acc2[1], 0, 0, 0);
  }

  float ssi = ss[b * KK + i];
  float* out_s = (float*)&wt_s[0][0];
  float bo = (lr < LL) ? b_out[lr] : 0.f;
  #pragma unroll
  for (int rt = 0; rt < 2; ++rt)
    #pragma unroll
    for (int q = 0; q < 4; ++q) {
      int row = rb + rt * 16 + lg * 4 + q;
      if (lr < LL) out_s[row * 12 + lr] = acc2[rt][q] + bo + ssi + ssj_s[row];
    }
  __syncthreads();
  size_t base = ((size_t)(b * KK + i) * KK + j0) * LL;
  for (int idx = t; idx < 128 * LL; idx += 256) {
    int j = idx / LL, ll2 = idx - j * LL;
    rel[base + idx] = out_s[j * 12 + ll2];
  }
}

// ---------------- ctxt via MFMA: 11 batched GEMMs + a_w combine ----------------
// ctxt[b,j,d] = inv * sum_l a_w[l,d] * sum_i probsT[b,l,j,i] * updT[b,d,i]
__global__ __launch_bounds__(256) void k_ctxt_mfma(
    const short* __restrict__ probsT, const short* __restrict__ updT,
    const float* __restrict__ a_w, const float* __restrict__ span_len,
    float* __restrict__ ctxt, short* __restrict__ ctxbf)
{
  int bidx = blockIdx.x;              // B * 4 * 12 = 96
  int b = bidx / 48;
  int r = bidx - b * 48;
  int jt = r / 12, dt = r - jt * 12;
  int j0 = jt * 64, d0 = dt * 64;

  __shared__ short Bs[64][BPAD];      // updT tile [d][i]
  __shared__ short As[64][BPAD];      // probsT tile [j][i] for current l

  int t = threadIdx.x, l = t & 63, w = t >> 6, lr = l & 15, lg = l >> 4;

  // stage B once: rows = d_local, 512 B each, coalesced
  for (int idx = t; idx < 2048; idx += 256) {
    int row = idx >> 5, c = idx & 31;
    *(short8*)&Bs[row][c * 8] =
        *(const short8*)(updT + ((size_t)(b * DD + d0 + row)) * KK + c * 8);
  }

  f32x4 accF[4];
  #pragma unroll
  for (int nt = 0; nt < 4; ++nt) accF[nt] = (f32x4){0.f, 0.f, 0.f, 0.f};

  for (int ll = 0; ll < LL; ++ll) {
    __syncthreads();                  // protect As (and first-pass Bs)
    for (int idx = t; idx < 2048; idx += 256) {
      int row = idx >> 5, c = idx & 31;
      *(short8*)&As[row][c * 8] =
          *(const short8*)(probsT + (((size_t)(b * LL + ll)) * KK + j0 + row) * KK + c * 8);
    }
    float awl[4];
    #pragma unroll
    for (int nt = 0; nt < 4; ++nt) awl[nt] = a_w[ll * DD + d0 + nt * 16 + lr];
    __syncthreads();

    f32x4 accL[4];
    #pragma unroll
    for (int nt = 0; nt < 4; ++nt) accL[nt] = (f32x4){0.f, 0.f, 0.f, 0.f};
    #pragma unroll
    for (int ks = 0; ks < 8; ++ks) {
      short8 a = *(short8*)&As[w * 16 + lr][ks * 32 + lg * 8];
      #pragma unroll
      for (int nt = 0; nt < 4; ++nt) {
        short8 bf = *(short8*)&Bs[nt * 16 + lr][ks * 32 + lg * 8];
        accL[nt] = __builtin_amdgcn_mfma_f32_16x16x32_bf16(a, bf, accL[nt], 0, 0, 0);
      }
    }
    #pragma unroll
    for (int nt = 0; nt < 4; ++nt)
      #pragma unroll
      for (int q = 0; q < 4; ++q)
        accF[nt][q] = fmaf(awl[nt], accL[nt][q], accF[nt][q]);
  }

  float inv = 1.f / span_len[b];
  int rowb = j0 + w * 16 + lg * 4;
  #pragma unroll
  for (int nt = 0; nt < 4; ++nt) {
    int col = d0 + nt * 16 + lr;
    #pragma unroll
    for (int q = 0; q < 4; ++q) {
      size_t off = (size_t)(b * KK + rowb + q) * DD + col;
      float v = accF[nt][q] * inv;
      ctxt[off] = v;
      ctxbf[off] = (short)f2bfu(v);
    }
  }
}

// ---------------- gate via MFMA: 64x64 tiles, K=1536 ----------------
__global__ __launch_bounds__(256) void k_gate_mfma(
    const short* __restrict__ updbf, const short* __restrict__ ctxbf,
    const short* __restrict__ gwt, const float* __restrict__ gate_b,
    const float* __restrict__ ctxt, float* __restrict__ upd,
    short* __restrict__ nxtbf)
{
  int rb = blockIdx.x / 12, cb = blockIdx.x - rb * 12;
  int row0 = rb * 64, col0 = cb * 64;
  __shared__ short As[64][WP];
  __shared__ short Bs[64][WP];
  int t = threadIdx.x, l = t & 63, w = t >> 6, lr = l & 15, lg = l >> 4;
  int r = t >> 2, c = t & 3;
  size_t arow = (size_t)(row0 + r) * DD;
  size_t brow = (size_t)(col0 + r) * (2 * DD);

  f32x4 acc[4];
  #pragma unroll
  for (int nt = 0; nt < 4; ++nt) acc[nt] = (f32x4){0.f, 0.f, 0.f, 0.f};

  short8 pa = *(const short8*)(updbf + arow + c * 8);
  short8 pb = *(const short8*)(gwt + brow + c * 8);
  for (int ks = 0; ks < 48; ++ks) {
    __syncthreads();
    *(short8*)&As[r][c * 8] = pa;
    *(short8*)&Bs[r][c * 8] = pb;
    __syncthreads();
    if (ks + 1 < 48) {
      int k0 = (ks + 1) * 32;
      const short* asrc = (k0 < DD) ? (updbf + arow + k0) : (ctxbf + arow + k0 - DD);
      pa = *(const short8*)(asrc + c * 8);
      pb = *(const short8*)(gwt + brow + k0 + c * 8);
    }
    short8 a = *(short8*)&As[w * 16 + lr][lg * 8];
    #pragma unroll
    for (int nt = 0; nt < 4; ++nt) {
      short8 b = *(short8*)&Bs[nt * 16 + lr][lg * 8];
      acc[nt] = __builtin_amdgcn_mfma_f32_16x16x32_bf16(a, b, acc[nt], 0, 0, 0);
    }
  }
  int rowb = row0 + w * 16 + lg * 4;
  #pragma unroll
  for (int nt = 0; nt < 4; ++nt) {
    int col = col0 + nt * 16 + lr;
    float gb = gate_b[col];
    #pragma unroll
    for (int q = 0; q < 4; ++q) {
      size_t off = (size_t)(rowb + q) * DD + col;
      float x = acc[nt][q] + gb;
      float g = 1.f / (1.f + expf(-x));
      float o = g * upd[off] + (1.f - g) * ctxt[off];
      upd[off] = o;
      nxtbf[off] = (short)f2bfu(o);
    }
  }
}

// ---------------- scatter ----------------
__global__ void k_scatter(const float* __restrict__ upd,
                          const int* __restrict__ prune_idx,
                          const float* __restrict__ span_len,
                          float* __restrict__ out_all)
{
  int b = blockIdx.x / KK;
  int k = blockIdx.x - b * KK;
  if ((float)k < span_len[b]) {
    int dst = prune_idx[b * KK + k];
    const float4* src = (const float4*)(upd + ((size_t)(b * KK + k)) * DD);
    float4* d = (float4*)(out_all + ((size_t)b * NN + dst) * DD);
    for (int idx = threadIdx.x; idx < DD / 4; idx += blockDim.x) d[idx] = src[idx];
  }
}

extern "C" void kernel_launch(void* const* d_in, const int* in_sizes, int n_in,
                              void* d_out, int out_size, void* d_ws, size_t ws_size,
                              hipStream_t stream)
{
  (void)in_sizes; (void)n_in; (void)out_size; (void)ws_size;
  const float* all_span = (const float*)d_in[0];
  const float* upd_in   = (const float*)d_in[1];
  const float* mask     = (const float*)d_in[2];
  const float* span_len = (const float*)d_in[3];
  const int*   span_beg = (const int*)d_in[4];
  const int*   prune    = (const int*)d_in[6];
  const float* w_left   = (const float*)d_in[7];
  const float* b_left   = (const float*)d_in[8];
  const float* w_right  = (const float*)d_in[9];
  const float* b_right  = (const float*)d_in[10];
  const float* dist_emb = (const float*)d_in[11];
  const float* w_h      = (const float*)d_in[12];
  const float* b_h      = (const float*)d_in[13];
  const float* w_out    = (const float*)d_in[14];
  const float* b_out    = (const float*)d_in[15];
  const float* a_w      = (const float*)d_in[16];
  const float* gate_w   = (const float*)d_in[17];
  const float* gate_b   = (const float*)d_in[18];
  const float* pr_w     = (const float*)d_in[19];
  const float* pr_b     = (const float*)d_in[20];

  float* out_all = (float*)d_out;
  float* out_upd = out_all + (size_t)BB * NN * DD;
  float* out_rel = out_upd + (size_t)BB * KK * DD;

  float* ws     = (float*)d_ws;
  float* left   = ws;                                   // 512*150
  float* right  = left + (size_t)BB * KK * HH;          // 512*150
  float* ssv    = right + (size_t)BB * KK * HH;         // 512
  float* ctxt   = ssv + (size_t)BB * KK;                // 512*768
  short* wt_bf  = (short*)(ctxt + (size_t)BB * KK * DD);// 160*160
  short* wo_bf  = wt_bf + KP * KP;                      // 16*160
  short* updbf0 = wo_bf + 16 * KP;                      // 512*768
  short* updbf1 = updbf0 + (size_t)BB * KK * DD;
  short* ctxbf  = updbf1 + (size_t)BB * KK * DD;
  short* gwt    = ctxbf + (size_t)BB * KK * DD;         // 768*1536
  short* wlrt   = gwt + (size_t)DD * 2 * DD;            // 320*768
  short* probsT = wlrt + (size_t)2 * KP * DD;           // 2*11*256*256
  short* updT   = probsT + (size_t)BB * LL * KK * KK;   // 2*768*256

  const int nupd = BB * KK * DD;

  hipMemcpyAsync(out_all, all_span, sizeof(float) * (size_t)BB * NN * DD,
                 hipMemcpyDeviceToDevice, stream);
  hipMemcpyAsync(out_upd, upd_in, sizeof(float) * (size_t)BB * KK * DD,
                 hipMemcpyDeviceToDevice, stream);
  k_prep<<<(KP * KP + 16 * KP + 255) / 256, 256, 0, stream>>>(w_h, w_out, wt_bf, wo_bf);
  k_cvt<<<(nupd + 255) / 256, 256, 0, stream>>>(upd_in, updbf0, nupd);
  k_tr_gw<<<48 * 24, 256, 0, stream>>>(gate_w, gwt);
  k_tr_wlr<<<24 * 10, 256, 0, stream>>>(w_left, w_right, wlrt);

  k_proj_mfma<<<16, 256, 0, stream>>>(updbf0, wlrt, b_left, b_right, left, right);
  k_ss<<<BB * KK / 4, 256, 0, stream>>>(out_upd, pr_w, pr_b, ssv);
  k_pair_mfma<<<BB * KK * 2, 256, 0, stream>>>(left, right, ssv, span_beg, dist_emb,
                                               wt_bf, wo_bf, b_h, b_out, out_rel);

  for (int p = 0; p < 2; ++p) {
    short* cur_bf = (p == 0) ? updbf0 : updbf1;
    short* nxt_bf = (p == 0) ? updbf1 : updbf0;
    k_tr_upd<<<BB * 8 * 24, 256, 0, stream>>>(out_upd, updT);
    k_ptr<<<BB * 8 * 8, 256, 0, stream>>>(out_rel, mask, probsT);
    k_ctxt_mfma<<<96, 256, 0, stream>>>(probsT, updT, a_w, span_len, ctxt, ctxbf);
    k_gate_mfma<<<8 * 12, 256, 0, stream>>>(cur_bf, ctxbf, gwt, gate_b, ctxt,
                                            out_upd, nxt_bf);
    k_proj_mfma<<<16, 256, 0, stream>>>(nxt_bf, wlrt, b_left, b_right, left, right);
    k_ss<<<BB * KK / 4, 256, 0, stream>>>(out_upd, pr_w, pr_b, ssv);
    k_pair_mfma<<<BB * KK * 2, 256, 0, stream>>>(left, right, ssv, span_beg, dist_emb,
                                                 wt_bf, wo_bf, b_h, b_out, out_rel);
  }
  k_scatter<<<BB * KK, 192, 0, stream>>>(out_upd, prune, span_len, out_all);
}

// Round 5
// 270.432 us; speedup vs baseline: 5.1122x; 1.3300x over previous
//
#include <hip/hip_runtime.h>
#include <math.h>

#define BB 2
#define NN 2048
#define KK 256
#define DD 768
#define HH 150
#define LL 11
#define NBINS 10

#define KP 160          // padded K/N for MFMA tiles
#define RP 168          // legacy pad (k_ptr tile etc.)
#define RPS 192         // swizzled h0 row stride in shorts (24 chunks of 8)
#define WP 40           // staged k-slice row stride in shorts
#define GWP 72          // gate K-step-64 row stride in shorts
#define BPAD 264        // 256-i row stride in shorts (ctxt staging)

typedef __attribute__((ext_vector_type(8))) short short8;
typedef __attribute__((ext_vector_type(4))) short s16x4;
typedef __attribute__((ext_vector_type(4))) float f32x4;

__device__ inline unsigned f2bfu(float x) {
  unsigned u = __float_as_uint(x);
  unsigned r = ((u >> 16) & 1u) + 0x7fffu;
  return (u + r) >> 16;
}

// ---------------- prep: bf16 zero-padded transposed pair weights ----------------
__global__ void k_prep(const float* __restrict__ w_h, const float* __restrict__ w_out,
                       short* __restrict__ wt, short* __restrict__ wo) {
  int idx = blockIdx.x * 256 + threadIdx.x;
  if (idx < KP * KP) {
    int n = idx / KP, k = idx - n * KP;
    float v = (n < HH && k < HH) ? w_h[k * HH + n] : 0.f;
    wt[idx] = (short)f2bfu(v);
  }
  int idx2 = idx - KP * KP;
  if (idx2 >= 0 && idx2 < 16 * KP) {
    int n = idx2 / KP, k = idx2 - n * KP;
    float v = (n < LL && k < HH) ? w_out[k * LL + n] : 0.f;
    wo[idx2] = (short)f2bfu(v);
  }
}

// ---------------- f32 -> bf16 convert ----------------
__global__ void k_cvt(const float* __restrict__ src, short* __restrict__ dst, int n) {
  int idx = blockIdx.x * 256 + threadIdx.x;
  if (idx < n) dst[idx] = (short)f2bfu(src[idx]);
}

// ---------------- tiled transpose gate_w [1536][768] -> gwt bf16 [768][1536] ----------------
__global__ __launch_bounds__(256) void k_tr_gw(const float* __restrict__ gate_w,
                                               short* __restrict__ gwt) {
  __shared__ float tile[32][33];
  int kt = blockIdx.x % 48, nt = blockIdx.x / 48;
  int m0 = kt * 32, n0 = nt * 32;
  int tx = threadIdx.x & 31, ty = threadIdx.x >> 5;
  #pragma unroll
  for (int r = 0; r < 4; ++r)
    tile[ty + r * 8][tx] = gate_w[(size_t)(m0 + ty + r * 8) * DD + n0 + tx];
  __syncthreads();
  #pragma unroll
  for (int r = 0; r < 4; ++r)
    gwt[(size_t)(n0 + ty + r * 8) * (2 * DD) + m0 + tx] = (short)f2bfu(tile[tx][ty + r * 8]);
}

// ---------------- tiled transpose w_left/w_right [768][150] -> wlrt bf16 [320][768] ----------------
__global__ __launch_bounds__(256) void k_tr_wlr(const float* __restrict__ w_left,
                                                const float* __restrict__ w_right,
                                                short* __restrict__ wlrt) {
  __shared__ float tile[32][33];
  int kt = blockIdx.x % 24, nt = blockIdx.x / 24;
  int k0 = kt * 32, n0 = nt * 32;
  const float* src = (n0 >= KP) ? w_right : w_left;
  int col0 = n0 - (n0 >= KP ? KP : 0);
  int tx = threadIdx.x & 31, ty = threadIdx.x >> 5;
  #pragma unroll
  for (int r = 0; r < 4; ++r) {
    int col = col0 + tx;
    tile[ty + r * 8][tx] = (col < HH) ? src[(size_t)(k0 + ty + r * 8) * HH + col] : 0.f;
  }
  __syncthreads();
  #pragma unroll
  for (int r = 0; r < 4; ++r)
    wlrt[(size_t)(n0 + ty + r * 8) * DD + k0 + tx] = (short)f2bfu(tile[tx][ty + r * 8]);
}

// ---------------- tiled transpose upd f32 [B][256][768] -> updT bf16 [B][768][256] ----------------
__global__ __launch_bounds__(256) void k_tr_upd(const float* __restrict__ upd,
                                                short* __restrict__ updT) {
  __shared__ float tile[32][33];
  int bidx = blockIdx.x;              // B * 8 * 24
  int b = bidx / 192;
  int r = bidx - b * 192;
  int it = r & 7, dt = r >> 3;
  int i0 = it * 32, d0 = dt * 32;
  int tx = threadIdx.x & 31, ty = threadIdx.x >> 5;
  #pragma unroll
  for (int rr = 0; rr < 4; ++rr)
    tile[ty + rr * 8][tx] = upd[(size_t)(b * KK + i0 + ty + rr * 8) * DD + d0 + tx];
  __syncthreads();
  #pragma unroll
  for (int rr = 0; rr < 4; ++rr)
    updT[(size_t)(b * DD + d0 + ty + rr * 8) * KK + i0 + tx] = (short)f2bfu(tile[tx][ty + rr * 8]);
}

// ---------------- probs transpose: rel [b][i][j][l] -> probsT bf16 [b][l][j][i] ----------------
__global__ __launch_bounds__(256) void k_ptr(const float* __restrict__ rel,
                                             const float* __restrict__ mask,
                                             short* __restrict__ probsT) {
  __shared__ float tile[32][353];
  __shared__ float maskS[32][32];
  int bidx = blockIdx.x;              // B*8*8
  int b = bidx >> 6;
  int r = bidx & 63;
  int it = r >> 3, jt = r & 7;
  int i0 = it * 32, j0 = jt * 32;
  int t = threadIdx.x;
  for (int idx = t; idx < 32 * 352; idx += 256) {
    int ii = idx / 352, c = idx - ii * 352;
    tile[ii][c] = rel[(((size_t)(b * KK + i0 + ii)) * KK + j0) * LL + c];
  }
  for (int idx = t; idx < 1024; idx += 256) {
    int ii = idx >> 5, jj = idx & 31;
    maskS[ii][jj] = mask[((size_t)(b * KK + i0 + ii)) * KK + j0 + jj];
  }
  __syncthreads();
  for (int idx = t; idx < LL * 1024; idx += 256) {
    int l = idx >> 10;
    int rem = idx & 1023;
    int jj = rem >> 5, ii = rem & 31;
    float v = fmaxf(tile[ii][jj * LL + l], 0.f) * maskS[ii][jj];
    probsT[(((size_t)(b * LL + l)) * KK + j0 + jj) * KK + i0 + ii] = (short)f2bfu(v);
  }
}

// ---------------- pruner scores ss = upd . pr_w + pr_b (f32) ----------------
__global__ __launch_bounds__(256) void k_ss(const float* __restrict__ upd,
                                            const float* __restrict__ pr_w,
                                            const float* __restrict__ pr_b,
                                            float* __restrict__ ss) {
  int row = blockIdx.x * 4 + (threadIdx.x >> 6);
  int l = threadIdx.x & 63;
  float s = 0.f;
  for (int d = l; d < DD; d += 64) s = fmaf(upd[(size_t)row * DD + d], pr_w[d], s);
  #pragma unroll
  for (int off = 32; off > 0; off >>= 1) s += __shfl_down(s, off);
  if (l == 0) ss[row] = s + pr_b[0];
}

// ---------------- proj via MFMA ----------------
__global__ __launch_bounds__(256) void k_proj_mfma(
    const short* __restrict__ updbf, const short* __restrict__ wlrt,
    const float* __restrict__ b_left, const float* __restrict__ b_right,
    float* __restrict__ left, float* __restrict__ right)
{
  int rbk = blockIdx.x >> 1, half = blockIdx.x & 1;
  int row0 = rbk * 64;
  const short* wsrc = wlrt + (size_t)half * KP * DD;
  __shared__ short As[64][WP];
  __shared__ short Bs[KP][WP];
  int t = threadIdx.x, l = t & 63, w = t >> 6, lr = l & 15, lg = l >> 4;
  int ar = t >> 2, ac = t & 3;
  int i1 = t + 256, i2 = t + 512;
  f32x4 acc[10];
  #pragma unroll
  for (int nt = 0; nt < 10; ++nt) acc[nt] = (f32x4){0.f, 0.f, 0.f, 0.f};

  short8 pa, pb0, pb1, pb2 = {};
  pa  = *(const short8*)(updbf + (size_t)(row0 + ar) * DD + ac * 8);
  pb0 = *(const short8*)(wsrc + (size_t)(t >> 2) * DD + (t & 3) * 8);
  pb1 = *(const short8*)(wsrc + (size_t)(i1 >> 2) * DD + (i1 & 3) * 8);
  if (i2 < 640) pb2 = *(const short8*)(wsrc + (size_t)(i2 >> 2) * DD + (i2 & 3) * 8);

  for (int ks = 0; ks < 24; ++ks) {
    __syncthreads();
    *(short8*)&As[ar][ac * 8] = pa;
    *(short8*)&Bs[t >> 2][(t & 3) * 8] = pb0;
    *(short8*)&Bs[i1 >> 2][(i1 & 3) * 8] = pb1;
    if (i2 < 640) *(short8*)&Bs[i2 >> 2][(i2 & 3) * 8] = pb2;
    __syncthreads();
    if (ks + 1 < 24) {
      int k0 = (ks + 1) * 32;
      pa  = *(const short8*)(updbf + (size_t)(row0 + ar) * DD + k0 + ac * 8);
      pb0 = *(const short8*)(wsrc + (size_t)(t >> 2) * DD + k0 + (t & 3) * 8);
      pb1 = *(const short8*)(wsrc + (size_t)(i1 >> 2) * DD + k0 + (i1 & 3) * 8);
      if (i2 < 640) pb2 = *(const short8*)(wsrc + (size_t)(i2 >> 2) * DD + k0 + (i2 & 3) * 8);
    }
    short8 a = *(short8*)&As[w * 16 + lr][lg * 8];
    #pragma unroll
    for (int nt = 0; nt < 10; ++nt) {
      short8 b = *(short8*)&Bs[nt * 16 + lr][lg * 8];
      acc[nt] = __builtin_amdgcn_mfma_f32_16x16x32_bf16(a, b, acc[nt], 0, 0, 0);
    }
  }
  const float* bias = half ? b_right : b_left;
  float* dst = half ? right : left;
  int rowb = row0 + w * 16 + lg * 4;
  #pragma unroll
  for (int nt = 0; nt < 10; ++nt) {
    int col = nt * 16 + lr;
    if (col < HH) {
      float bv = bias[col];
      #pragma unroll
      for (int q = 0; q < 4; ++q)
        dst[(size_t)(rowb + q) * HH + col] = acc[nt][q] + bv;
    }
  }
}

// ---------------- pair scores via MFMA (v3: M=64, swizzled h0, demb in LDS) ----------------
__global__ __launch_bounds__(256) void k_pair_mfma(
    const float* __restrict__ left, const float* __restrict__ right,
    const float* __restrict__ ss, const int* __restrict__ span_begin,
    const float* __restrict__ demb,
    const short* __restrict__ wt, const short* __restrict__ wo,
    const float* __restrict__ b_h, const float* __restrict__ b_out,
    float* __restrict__ rel)
{
  int bid = blockIdx.x;
  int b  = bid >> 10;
  int r2 = bid & 1023;
  int i  = r2 >> 2;
  int j0 = (r2 & 3) * 64;

  __shared__ short h0[64][RPS];        // 24576 B, chunk-swizzled (chunk ^= row&7)
  __shared__ short wt_s[KP][WP];       // 12800 B; reused as f32 out_s[64][12]
  __shared__ float demb_s[NBINS][152]; // 6080 B
  __shared__ float left_s[152];
  __shared__ float bh_s[KP];
  __shared__ float ssj_s[64];
  __shared__ int   bins[64];

  int t = threadIdx.x;
  int l = t & 63, w = t >> 6;
  int lr = l & 15, lg = l >> 4;

  int sbi = span_begin[b * KK + i];
  for (int idx = t; idx < HH; idx += 256) left_s[idx] = left[(size_t)(b * KK + i) * HH + idx];
  for (int idx = t; idx < KP; idx += 256) bh_s[idx] = (idx < HH) ? b_h[idx] : 0.f;
  if (t < 64) {
    int d = span_begin[b * KK + j0 + t] - sbi; d = d < 0 ? -d : d;
    bins[t] = d > NBINS - 1 ? NBINS - 1 : d;
    ssj_s[t] = ss[b * KK + j0 + t];
  }
  for (int idx = t; idx < NBINS * HH; idx += 256) {
    int r = idx / HH, c = idx - r * HH;
    demb_s[r][c] = demb[idx];
  }

  // wo fragments in registers (GEMM2 B operand)
  short8 wo_f[5];
  #pragma unroll
  for (int ks = 0; ks < 5; ++ks)
    wo_f[ks] = *(const short8*)(wo + lr * KP + ks * 32 + lg * 8);

  // preload wt k-slice 0 into registers
  int i1 = t + 256, i2 = t + 512;
  short8 pw0, pw1, pw2 = {};
  pw0 = *(const short8*)(wt + (t >> 2) * KP + (t & 3) * 8);
  pw1 = *(const short8*)(wt + (i1 >> 2) * KP + (i1 & 3) * 8);
  if (i2 < 640) pw2 = *(const short8*)(wt + (i2 >> 2) * KP + (i2 & 3) * 8);

  __syncthreads();   // demb_s/left_s/bins/ssj ready

  // build h0 (64 rows x 160 cols + zero pad), chunk-swizzled
  for (int idx = t; idx < 64 * 84; idx += 256) {
    int r = idx / 84, mp = idx - r * 84;
    int m = mp * 2;
    int v = 0;
    if (mp < 75) {
      float2 rv = *(const float2*)(right + (size_t)(b * KK + j0 + r) * HH + m);
      const float* de = demb_s[bins[r]];
      float v0 = fmaxf(left_s[m]     + rv.x + de[m],     0.f);
      float v1 = fmaxf(left_s[m + 1] + rv.y + de[m + 1], 0.f);
      v = (int)(f2bfu(v0) | (f2bfu(v1) << 16));
    }
    int cc = (mp >> 2) ^ (r & 7);
    ((int*)&h0[r][0])[cc * 4 + (mp & 3)] = v;
  }

  f32x4 acc[10];
  #pragma unroll
  for (int nt = 0; nt < 10; ++nt) acc[nt] = (f32x4){0.f, 0.f, 0.f, 0.f};

  int arow = w * 16 + lr;
  int aswz = arow & 7;

  for (int ks = 0; ks < 5; ++ks) {
    __syncthreads();   // prior wt_s reads / h0 build done
    *(short8*)&wt_s[t >> 2][(t & 3) * 8] = pw0;
    *(short8*)&wt_s[i1 >> 2][(i1 & 3) * 8] = pw1;
    if (i2 < 640) *(short8*)&wt_s[i2 >> 2][(i2 & 3) * 8] = pw2;
    if (ks + 1 < 5) {
      int k0 = (ks + 1) * 32;
      pw0 = *(const short8*)(wt + (t >> 2) * KP + k0 + (t & 3) * 8);
      pw1 = *(const short8*)(wt + (i1 >> 2) * KP + k0 + (i1 & 3) * 8);
      if (i2 < 640) pw2 = *(const short8*)(wt + (i2 >> 2) * KP + k0 + (i2 & 3) * 8);
    }
    __syncthreads();
    short8 a = *(short8*)&h0[arow][((ks * 4 + lg) ^ aswz) * 8];
    #pragma unroll
    for (int nt = 0; nt < 10; ++nt) {
      short8 bf = *(short8*)&wt_s[nt * 16 + lr][lg * 8];
      acc[nt] = __builtin_amdgcn_mfma_f32_16x16x32_bf16(a, bf, acc[nt], 0, 0, 0);
    }
  }

  __syncthreads();   // GEMM1 h0 reads done
  // h1 = relu(acc + b_h) -> back into h0 (swizzled)
  #pragma unroll
  for (int nt = 0; nt < 10; ++nt) {
    int n = nt * 16 + lr;
    float bh = bh_s[n];
    #pragma unroll
    for (int q = 0; q < 4; ++q) {
      int row = w * 16 + lg * 4 + q;
      float hv = fmaxf(acc[nt][q] + bh, 0.f);
      h0[row][(((n >> 3) ^ (row & 7)) * 8) + (n & 7)] = (short)f2bfu(hv);
    }
  }
  __syncthreads();

  f32x4 acc2 = (f32x4){0.f, 0.f, 0.f, 0.f};
  #pragma unroll
  for (int ks = 0; ks < 5; ++ks) {
    short8 a = *(short8*)&h0[arow][((ks * 4 + lg) ^ aswz) * 8];
    acc2 = __builtin_amdgcn_mfma_f32_16x16x32_bf16(a, wo_f[ks], acc2, 0, 0, 0);
  }

  float ssi = ss[b * KK + i];
  float* out_s = (float*)&wt_s[0][0];
  if (lr < LL) {
    float bo = b_out[lr];
    #pragma unroll
    for (int q = 0; q < 4; ++q) {
      int row = w * 16 + lg * 4 + q;
      out_s[row * 12 + lr] = acc2[q] + bo + ssi + ssj_s[row];
    }
  }
  __syncthreads();
  size_t base = ((size_t)(b * KK + i) * KK + j0) * LL;
  for (int idx = t; idx < 64 * LL; idx += 256) {
    int j = idx / LL, ll2 = idx - j * LL;
    rel[base + idx] = out_s[j * 12 + ll2];
  }
}

// ---------------- ctxt via MFMA (v2: j-tile 32, 192 blocks, reg prefetch) ----------------
// ctxt[b,j,d] = inv * sum_l a_w[l,d] * sum_i probsT[b,l,j,i] * updT[b,d,i]
__global__ __launch_bounds__(256) void k_ctxt_mfma(
    const short* __restrict__ probsT, const short* __restrict__ updT,
    const float* __restrict__ a_w, const float* __restrict__ span_len,
    float* __restrict__ ctxt, short* __restrict__ ctxbf)
{
  int bidx = blockIdx.x;              // B * 8 * 12 = 192
  int b = bidx / 96;
  int r = bidx - b * 96;
  int jt = r / 12, dt = r - jt * 12;
  int j0 = jt * 32, d0 = dt * 64;

  __shared__ short Bs[64][BPAD];      // updT tile [d][i]
  __shared__ short As[32][BPAD];      // probsT tile [j][i] for current l

  int t = threadIdx.x, l = t & 63, w = t >> 6, lr = l & 15, lg = l >> 4;
  int wr = w >> 1, wc = w & 1;

  // stage B once
  for (int s = 0; s < 8; ++s) {
    int idx = t + s * 256;
    int row = idx >> 5, c = idx & 31;
    *(short8*)&Bs[row][c * 8] =
        *(const short8*)(updT + ((size_t)(b * DD + d0 + row)) * KK + c * 8);
  }

  // preload As for l=0
  short8 pa[4];
  #pragma unroll
  for (int s = 0; s < 4; ++s) {
    int idx = t + s * 256;
    int row = idx >> 5, c = idx & 31;
    pa[s] = *(const short8*)(probsT + (((size_t)(b * LL + 0)) * KK + j0 + row) * KK + c * 8);
  }

  f32x4 accF[2];
  accF[0] = (f32x4){0.f, 0.f, 0.f, 0.f};
  accF[1] = (f32x4){0.f, 0.f, 0.f, 0.f};

  for (int ll = 0; ll < LL; ++ll) {
    __syncthreads();                  // prior As reads done (and Bs staged, first pass)
    #pragma unroll
    for (int s = 0; s < 4; ++s) {
      int idx = t + s * 256;
      int row = idx >> 5, c = idx & 31;
      *(short8*)&As[row][c * 8] = pa[s];
    }
    if (ll + 1 < LL) {
      #pragma unroll
      for (int s = 0; s < 4; ++s) {
        int idx = t + s * 256;
        int row = idx >> 5, c = idx & 31;
        pa[s] = *(const short8*)(probsT + (((size_t)(b * LL + ll + 1)) * KK + j0 + row) * KK + c * 8);
      }
    }
    float awl[2];
    #pragma unroll
    for (int nt = 0; nt < 2; ++nt) awl[nt] = a_w[ll * DD + d0 + wc * 32 + nt * 16 + lr];
    __syncthreads();

    f32x4 accL[2];
    accL[0] = (f32x4){0.f, 0.f, 0.f, 0.f};
    accL[1] = (f32x4){0.f, 0.f, 0.f, 0.f};
    #pragma unroll
    for (int ks = 0; ks < 8; ++ks) {
      short8 a = *(short8*)&As[wr * 16 + lr][ks * 32 + lg * 8];
      #pragma unroll
      for (int nt = 0; nt < 2; ++nt) {
        short8 bf = *(short8*)&Bs[wc * 32 + nt * 16 + lr][ks * 32 + lg * 8];
        accL[nt] = __builtin_amdgcn_mfma_f32_16x16x32_bf16(a, bf, accL[nt], 0, 0, 0);
      }
    }
    #pragma unroll
    for (int nt = 0; nt < 2; ++nt)
      #pragma unroll
      for (int q = 0; q < 4; ++q)
        accF[nt][q] = fmaf(awl[nt], accL[nt][q], accF[nt][q]);
  }

  float inv = 1.f / span_len[b];
  int rowb = j0 + wr * 16 + lg * 4;
  #pragma unroll
  for (int nt = 0; nt < 2; ++nt) {
    int col = d0 + wc * 32 + nt * 16 + lr;
    #pragma unroll
    for (int q = 0; q < 4; ++q) {
      size_t off = (size_t)(b * KK + rowb + q) * DD + col;
      float v = accF[nt][q] * inv;
      ctxt[off] = v;
      ctxbf[off] = (short)f2bfu(v);
    }
  }
}

// ---------------- gate via MFMA (v2: 32x64 tiles, K-step 64, fused updT write) ----------------
__global__ __launch_bounds__(256) void k_gate_mfma(
    const short* __restrict__ updbf, const short* __restrict__ ctxbf,
    const short* __restrict__ gwt, const float* __restrict__ gate_b,
    const float* __restrict__ ctxt, float* __restrict__ upd,
    short* __restrict__ nxtbf, short* __restrict__ updT)
{
  int rb = blockIdx.x / 12, cb = blockIdx.x - rb * 12;
  int row0 = rb * 32, col0 = cb * 64;
  __shared__ short As[32][GWP];
  __shared__ short Bs[64][GWP];
  int t = threadIdx.x, l = t & 63, w = t >> 6, lr = l & 15, lg = l >> 4;
  int wr = w >> 1, wc = w & 1;

  int ar = t >> 3, ac = t & 7;        // A stage: 32 rows x 8 chunks
  int b1 = t + 256;

  f32x4 acc[2];
  acc[0] = (f32x4){0.f, 0.f, 0.f, 0.f};
  acc[1] = (f32x4){0.f, 0.f, 0.f, 0.f};

  // preload ks=0
  short8 pa = *(const short8*)(updbf + (size_t)(row0 + ar) * DD + ac * 8);
  short8 pb0 = *(const short8*)(gwt + (size_t)(col0 + (t >> 3)) * (2 * DD) + (t & 7) * 8);
  short8 pb1 = *(const short8*)(gwt + (size_t)(col0 + (b1 >> 3)) * (2 * DD) + (b1 & 7) * 8);

  for (int ks = 0; ks < 24; ++ks) {
    __syncthreads();
    *(short8*)&As[ar][ac * 8] = pa;
    *(short8*)&Bs[t >> 3][(t & 7) * 8] = pb0;
    *(short8*)&Bs[b1 >> 3][(b1 & 7) * 8] = pb1;
    if (ks + 1 < 24) {
      int k0 = (ks + 1) * 64;
      int ka = k0 + ac * 8;
      const short* asrc = (ka < DD) ? (updbf + (size_t)(row0 + ar) * DD + ka)
                                    : (ctxbf + (size_t)(row0 + ar) * DD + ka - DD);
      pa  = *(const short8*)asrc;
      pb0 = *(const short8*)(gwt + (size_t)(col0 + (t >> 3)) * (2 * DD) + k0 + (t & 7) * 8);
      pb1 = *(const short8*)(gwt + (size_t)(col0 + (b1 >> 3)) * (2 * DD) + k0 + (b1 & 7) * 8);
    }
    __syncthreads();
    #pragma unroll
    for (int ksub = 0; ksub < 2; ++ksub) {
      short8 a = *(short8*)&As[wr * 16 + lr][ksub * 32 + lg * 8];
      #pragma unroll
      for (int nt = 0; nt < 2; ++nt) {
        short8 bf = *(short8*)&Bs[wc * 32 + nt * 16 + lr][ksub * 32 + lg * 8];
        acc[nt] = __builtin_amdgcn_mfma_f32_16x16x32_bf16(a, bf, acc[nt], 0, 0, 0);
      }
    }
  }
  int rowb = row0 + wr * 16 + lg * 4;
  int bb = rowb >> 8, ii = rowb & 255;
  #pragma unroll
  for (int nt = 0; nt < 2; ++nt) {
    int col = col0 + wc * 32 + nt * 16 + lr;
    float gb = gate_b[col];
    s16x4 tw;
    #pragma unroll
    for (int q = 0; q < 4; ++q) {
      size_t off = (size_t)(rowb + q) * DD + col;
      float x = acc[nt][q] + gb;
      float g = 1.f / (1.f + expf(-x));
      float o = g * upd[off] + (1.f - g) * ctxt[off];
      upd[off] = o;
      short bv = (short)f2bfu(o);
      nxtbf[off] = bv;
      tw[q] = bv;
    }
    *(s16x4*)(updT + ((size_t)(bb * DD + col)) * KK + ii) = tw;
  }
}

// ---------------- scatter ----------------
__global__ void k_scatter(const float* __restrict__ upd,
                          const int* __restrict__ prune_idx,
                          const float* __restrict__ span_len,
                          float* __restrict__ out_all)
{
  int b = blockIdx.x / KK;
  int k = blockIdx.x - b * KK;
  if ((float)k < span_len[b]) {
    int dst = prune_idx[b * KK + k];
    const float4* src = (const float4*)(upd + ((size_t)(b * KK + k)) * DD);
    float4* d = (float4*)(out_all + ((size_t)b * NN + dst) * DD);
    for (int idx = threadIdx.x; idx < DD / 4; idx += blockDim.x) d[idx] = src[idx];
  }
}

extern "C" void kernel_launch(void* const* d_in, const int* in_sizes, int n_in,
                              void* d_out, int out_size, void* d_ws, size_t ws_size,
                              hipStream_t stream)
{
  (void)in_sizes; (void)n_in; (void)out_size; (void)ws_size;
  const float* all_span = (const float*)d_in[0];
  const float* upd_in   = (const float*)d_in[1];
  const float* mask     = (const float*)d_in[2];
  const float* span_len = (const float*)d_in[3];
  const int*   span_beg = (const int*)d_in[4];
  const int*   prune    = (const int*)d_in[6];
  const float* w_left   = (const float*)d_in[7];
  const float* b_left   = (const float*)d_in[8];
  const float* w_right  = (const float*)d_in[9];
  const float* b_right  = (const float*)d_in[10];
  const float* dist_emb = (const float*)d_in[11];
  const float* w_h      = (const float*)d_in[12];
  const float* b_h      = (const float*)d_in[13];
  const float* w_out    = (const float*)d_in[14];
  const float* b_out    = (const float*)d_in[15];
  const float* a_w      = (const float*)d_in[16];
  const float* gate_w   = (const float*)d_in[17];
  const float* gate_b   = (const float*)d_in[18];
  const float* pr_w     = (const float*)d_in[19];
  const float* pr_b     = (const float*)d_in[20];

  float* out_all = (float*)d_out;
  float* out_upd = out_all + (size_t)BB * NN * DD;
  float* out_rel = out_upd + (size_t)BB * KK * DD;

  float* ws     = (float*)d_ws;
  float* left   = ws;                                   // 512*150
  float* right  = left + (size_t)BB * KK * HH;          // 512*150
  float* ssv    = right + (size_t)BB * KK * HH;         // 512
  float* ctxt   = ssv + (size_t)BB * KK;                // 512*768
  short* wt_bf  = (short*)(ctxt + (size_t)BB * KK * DD);// 160*160
  short* wo_bf  = wt_bf + KP * KP;                      // 16*160
  short* updbf0 = wo_bf + 16 * KP;                      // 512*768
  short* updbf1 = updbf0 + (size_t)BB * KK * DD;
  short* ctxbf  = updbf1 + (size_t)BB * KK * DD;
  short* gwt    = ctxbf + (size_t)BB * KK * DD;         // 768*1536
  short* wlrt   = gwt + (size_t)DD * 2 * DD;            // 320*768
  short* probsT = wlrt + (size_t)2 * KP * DD;           // 2*11*256*256
  short* updT   = probsT + (size_t)BB * LL * KK * KK;   // 2*768*256

  const int nupd = BB * KK * DD;

  hipMemcpyAsync(out_all, all_span, sizeof(float) * (size_t)BB * NN * DD,
                 hipMemcpyDeviceToDevice, stream);
  hipMemcpyAsync(out_upd, upd_in, sizeof(float) * (size_t)BB * KK * DD,
                 hipMemcpyDeviceToDevice, stream);
  k_prep<<<(KP * KP + 16 * KP + 255) / 256, 256, 0, stream>>>(w_h, w_out, wt_bf, wo_bf);
  k_cvt<<<(nupd + 255) / 256, 256, 0, stream>>>(upd_in, updbf0, nupd);
  k_tr_gw<<<48 * 24, 256, 0, stream>>>(gate_w, gwt);
  k_tr_wlr<<<24 * 10, 256, 0, stream>>>(w_left, w_right, wlrt);
  k_tr_upd<<<BB * 8 * 24, 256, 0, stream>>>(upd_in, updT);

  k_proj_mfma<<<16, 256, 0, stream>>>(updbf0, wlrt, b_left, b_right, left, right);
  k_ss<<<BB * KK / 4, 256, 0, stream>>>(out_upd, pr_w, pr_b, ssv);
  k_pair_mfma<<<BB * KK * 4, 256, 0, stream>>>(left, right, ssv, span_beg, dist_emb,
                                               wt_bf, wo_bf, b_h, b_out, out_rel);

  for (int p = 0; p < 2; ++p) {
    short* cur_bf = (p == 0) ? updbf0 : updbf1;
    short* nxt_bf = (p == 0) ? updbf1 : updbf0;
    k_ptr<<<BB * 8 * 8, 256, 0, stream>>>(out_rel, mask, probsT);
    k_ctxt_mfma<<<BB * 8 * 12, 256, 0, stream>>>(probsT, updT, a_w, span_len, ctxt, ctxbf);
    k_gate_mfma<<<16 * 12, 256, 0, stream>>>(cur_bf, ctxbf, gwt, gate_b, ctxt,
                                             out_upd, nxt_bf, updT);
    k_proj_mfma<<<16, 256, 0, stream>>>(nxt_bf, wlrt, b_left, b_right, left, right);
    k_ss<<<BB * KK / 4, 256, 0, stream>>>(out_upd, pr_w, pr_b, ssv);
    k_pair_mfma<<<BB * KK * 4, 256, 0, stream>>>(left, right, ssv, span_beg, dist_emb,
                                                 wt_bf, wo_bf, b_h, b_out, out_rel);
  }
  k_scatter<<<BB * KK, 192, 0, stream>>>(out_upd, prune, span_len, out_all);
}

// Round 6
// 222.406 us; speedup vs baseline: 6.2161x; 1.2159x over previous
//
#include <hip/hip_runtime.h>
#include <math.h>

#define BB 2
#define NN 2048
#define KK 256
#define DD 768
#define HH 150
#define LL 11
#define NBINS 10

#define KP 160          // padded K/N for MFMA tiles
#define WP 40           // staged k-slice row stride in shorts (proj)
#define GWP 72          // gate K-step-64 row stride in shorts
#define BPAD 264        // 256-i row stride in shorts (ctxt staging)

typedef __attribute__((ext_vector_type(8))) short short8;
typedef __attribute__((ext_vector_type(4))) short s16x4;
typedef __attribute__((ext_vector_type(4))) float f32x4;

__device__ inline unsigned f2bfu(float x) {
  unsigned u = __float_as_uint(x);
  unsigned r = ((u >> 16) & 1u) + 0x7fffu;
  return (u + r) >> 16;
}

// ---------------- prep: bf16 zero-padded transposed pair weights ----------------
__global__ void k_prep(const float* __restrict__ w_h, const float* __restrict__ w_out,
                       short* __restrict__ wt, short* __restrict__ wo) {
  int idx = blockIdx.x * 256 + threadIdx.x;
  if (idx < KP * KP) {
    int n = idx / KP, k = idx - n * KP;
    float v = (n < HH && k < HH) ? w_h[k * HH + n] : 0.f;
    wt[idx] = (short)f2bfu(v);
  }
  int idx2 = idx - KP * KP;
  if (idx2 >= 0 && idx2 < 16 * KP) {
    int n = idx2 / KP, k = idx2 - n * KP;
    float v = (n < LL && k < HH) ? w_out[k * LL + n] : 0.f;
    wo[idx2] = (short)f2bfu(v);
  }
}

// ---------------- f32 -> bf16 convert ----------------
__global__ void k_cvt(const float* __restrict__ src, short* __restrict__ dst, int n) {
  int idx = blockIdx.x * 256 + threadIdx.x;
  if (idx < n) dst[idx] = (short)f2bfu(src[idx]);
}

// ---------------- tiled transpose gate_w [1536][768] -> gwt bf16 [768][1536] ----------------
__global__ __launch_bounds__(256) void k_tr_gw(const float* __restrict__ gate_w,
                                               short* __restrict__ gwt) {
  __shared__ float tile[32][33];
  int kt = blockIdx.x % 48, nt = blockIdx.x / 48;
  int m0 = kt * 32, n0 = nt * 32;
  int tx = threadIdx.x & 31, ty = threadIdx.x >> 5;
  #pragma unroll
  for (int r = 0; r < 4; ++r)
    tile[ty + r * 8][tx] = gate_w[(size_t)(m0 + ty + r * 8) * DD + n0 + tx];
  __syncthreads();
  #pragma unroll
  for (int r = 0; r < 4; ++r)
    gwt[(size_t)(n0 + ty + r * 8) * (2 * DD) + m0 + tx] = (short)f2bfu(tile[tx][ty + r * 8]);
}

// ---------------- tiled transpose w_left/w_right [768][150] -> wlrt bf16 [320][768] ----------------
__global__ __launch_bounds__(256) void k_tr_wlr(const float* __restrict__ w_left,
                                                const float* __restrict__ w_right,
                                                short* __restrict__ wlrt) {
  __shared__ float tile[32][33];
  int kt = blockIdx.x % 24, nt = blockIdx.x / 24;
  int k0 = kt * 32, n0 = nt * 32;
  const float* src = (n0 >= KP) ? w_right : w_left;
  int col0 = n0 - (n0 >= KP ? KP : 0);
  int tx = threadIdx.x & 31, ty = threadIdx.x >> 5;
  #pragma unroll
  for (int r = 0; r < 4; ++r) {
    int col = col0 + tx;
    tile[ty + r * 8][tx] = (col < HH) ? src[(size_t)(k0 + ty + r * 8) * HH + col] : 0.f;
  }
  __syncthreads();
  #pragma unroll
  for (int r = 0; r < 4; ++r)
    wlrt[(size_t)(n0 + ty + r * 8) * DD + k0 + tx] = (short)f2bfu(tile[tx][ty + r * 8]);
}

// ---------------- tiled transpose upd f32 [B][256][768] -> updT bf16 [B][768][256] ----------------
__global__ __launch_bounds__(256) void k_tr_upd(const float* __restrict__ upd,
                                                short* __restrict__ updT) {
  __shared__ float tile[32][33];
  int bidx = blockIdx.x;              // B * 8 * 24
  int b = bidx / 192;
  int r = bidx - b * 192;
  int it = r & 7, dt = r >> 3;
  int i0 = it * 32, d0 = dt * 32;
  int tx = threadIdx.x & 31, ty = threadIdx.x >> 5;
  #pragma unroll
  for (int rr = 0; rr < 4; ++rr)
    tile[ty + rr * 8][tx] = upd[(size_t)(b * KK + i0 + ty + rr * 8) * DD + d0 + tx];
  __syncthreads();
  #pragma unroll
  for (int rr = 0; rr < 4; ++rr)
    updT[(size_t)(b * DD + d0 + ty + rr * 8) * KK + i0 + tx] = (short)f2bfu(tile[tx][ty + rr * 8]);
}

// ---------------- probs transpose: rel [b][i][j][l] -> probsT bf16 [b][l][j][i] ----------------
__global__ __launch_bounds__(256) void k_ptr(const float* __restrict__ rel,
                                             const float* __restrict__ mask,
                                             short* __restrict__ probsT) {
  __shared__ float tile[32][353];
  __shared__ float maskS[32][32];
  int bidx = blockIdx.x;              // B*8*8
  int b = bidx >> 6;
  int r = bidx & 63;
  int it = r >> 3, jt = r & 7;
  int i0 = it * 32, j0 = jt * 32;
  int t = threadIdx.x;
  for (int idx = t; idx < 32 * 352; idx += 256) {
    int ii = idx / 352, c = idx - ii * 352;
    tile[ii][c] = rel[(((size_t)(b * KK + i0 + ii)) * KK + j0) * LL + c];
  }
  for (int idx = t; idx < 1024; idx += 256) {
    int ii = idx >> 5, jj = idx & 31;
    maskS[ii][jj] = mask[((size_t)(b * KK + i0 + ii)) * KK + j0 + jj];
  }
  __syncthreads();
  for (int idx = t; idx < LL * 1024; idx += 256) {
    int l = idx >> 10;
    int rem = idx & 1023;
    int jj = rem >> 5, ii = rem & 31;
    float v = fmaxf(tile[ii][jj * LL + l], 0.f) * maskS[ii][jj];
    probsT[(((size_t)(b * LL + l)) * KK + j0 + jj) * KK + i0 + ii] = (short)f2bfu(v);
  }
}

// ---------------- pruner scores ss = upd . pr_w + pr_b (f32) ----------------
__global__ __launch_bounds__(256) void k_ss(const float* __restrict__ upd,
                                            const float* __restrict__ pr_w,
                                            const float* __restrict__ pr_b,
                                            float* __restrict__ ss) {
  int row = blockIdx.x * 4 + (threadIdx.x >> 6);
  int l = threadIdx.x & 63;
  float s = 0.f;
  for (int d = l; d < DD; d += 64) s = fmaf(upd[(size_t)row * DD + d], pr_w[d], s);
  #pragma unroll
  for (int off = 32; off > 0; off >>= 1) s += __shfl_down(s, off);
  if (l == 0) ss[row] = s + pr_b[0];
}

// ---------------- proj via MFMA ----------------
__global__ __launch_bounds__(256) void k_proj_mfma(
    const short* __restrict__ updbf, const short* __restrict__ wlrt,
    const float* __restrict__ b_left, const float* __restrict__ b_right,
    float* __restrict__ left, float* __restrict__ right)
{
  int rbk = blockIdx.x >> 1, half = blockIdx.x & 1;
  int row0 = rbk * 64;
  const short* wsrc = wlrt + (size_t)half * KP * DD;
  __shared__ short As[64][WP];
  __shared__ short Bs[KP][WP];
  int t = threadIdx.x, l = t & 63, w = t >> 6, lr = l & 15, lg = l >> 4;
  int ar = t >> 2, ac = t & 3;
  int i1 = t + 256, i2 = t + 512;
  f32x4 acc[10];
  #pragma unroll
  for (int nt = 0; nt < 10; ++nt) acc[nt] = (f32x4){0.f, 0.f, 0.f, 0.f};

  short8 pa, pb0, pb1, pb2 = {};
  pa  = *(const short8*)(updbf + (size_t)(row0 + ar) * DD + ac * 8);
  pb0 = *(const short8*)(wsrc + (size_t)(t >> 2) * DD + (t & 3) * 8);
  pb1 = *(const short8*)(wsrc + (size_t)(i1 >> 2) * DD + (i1 & 3) * 8);
  if (i2 < 640) pb2 = *(const short8*)(wsrc + (size_t)(i2 >> 2) * DD + (i2 & 3) * 8);

  for (int ks = 0; ks < 24; ++ks) {
    __syncthreads();
    *(short8*)&As[ar][ac * 8] = pa;
    *(short8*)&Bs[t >> 2][(t & 3) * 8] = pb0;
    *(short8*)&Bs[i1 >> 2][(i1 & 3) * 8] = pb1;
    if (i2 < 640) *(short8*)&Bs[i2 >> 2][(i2 & 3) * 8] = pb2;
    __syncthreads();
    if (ks + 1 < 24) {
      int k0 = (ks + 1) * 32;
      pa  = *(const short8*)(updbf + (size_t)(row0 + ar) * DD + k0 + ac * 8);
      pb0 = *(const short8*)(wsrc + (size_t)(t >> 2) * DD + k0 + (t & 3) * 8);
      pb1 = *(const short8*)(wsrc + (size_t)(i1 >> 2) * DD + k0 + (i1 & 3) * 8);
      if (i2 < 640) pb2 = *(const short8*)(wsrc + (size_t)(i2 >> 2) * DD + k0 + (i2 & 3) * 8);
    }
    short8 a = *(short8*)&As[w * 16 + lr][lg * 8];
    #pragma unroll
    for (int nt = 0; nt < 10; ++nt) {
      short8 b = *(short8*)&Bs[nt * 16 + lr][lg * 8];
      acc[nt] = __builtin_amdgcn_mfma_f32_16x16x32_bf16(a, b, acc[nt], 0, 0, 0);
    }
  }
  const float* bias = half ? b_right : b_left;
  float* dst = half ? right : left;
  int rowb = row0 + w * 16 + lg * 4;
  #pragma unroll
  for (int nt = 0; nt < 10; ++nt) {
    int col = nt * 16 + lr;
    if (col < HH) {
      float bv = bias[col];
      #pragma unroll
      for (int q = 0; q < 4; ++q)
        dst[(size_t)(rowb + q) * HH + col] = acc[nt][q] + bv;
    }
  }
}

// ---------------- pair scores via MFMA (v4: register-direct A, 5-slice wt pipeline) ----------------
// block = (b, i, 64-j quarter). A-fragment for lane = row w*16+lr, k-slice ks*32+lg*8
// computed IN REGISTERS from ld_s[bin][k] (= left_i + demb) + right[j][k]. No h0 tile.
// wt pipelined through 2x(32x160) LDS slices; h1 transpose tile reuses the wt buffer.
__global__ __launch_bounds__(256, 4) void k_pair_mfma(
    const float* __restrict__ left, const float* __restrict__ right,
    const float* __restrict__ ss, const int* __restrict__ span_begin,
    const float* __restrict__ demb,
    const short* __restrict__ wt, const short* __restrict__ wo,
    const float* __restrict__ b_h, const float* __restrict__ b_out,
    float* __restrict__ rel)
{
  int bid = blockIdx.x;
  int b  = bid >> 10;
  int r2 = bid & 1023;
  int i  = r2 >> 2;
  int j0 = (r2 & 3) * 64;

  __shared__ short wtbuf[2][32 * KP];   // 20480 B; after GEMM1 reused as h1 [64][160]
  __shared__ float ld_s[NBINS][168];    // 6720 B (left_i + demb); reused as out_s f32[64][12]
  __shared__ float bh_s[KP];
  __shared__ float ssj_s[64];
  __shared__ int   bins[64];

  int t = threadIdx.x;
  int l = t & 63, w = t >> 6;
  int lr = l & 15, lg = l >> 4;

  // ---- phase 0: stage ld_s/bins/ssj/bh; wo_f regs; slice-0 of wt -> buf0; prefetch slice-1
  int sbi = span_begin[b * KK + i];
  if (t < 64) {
    int d = span_begin[b * KK + j0 + t] - sbi; d = d < 0 ? -d : d;
    bins[t] = d > NBINS - 1 ? NBINS - 1 : d;
    ssj_s[t] = ss[b * KK + j0 + t];
  }
  for (int idx = t; idx < KP; idx += 256) bh_s[idx] = (idx < HH) ? b_h[idx] : 0.f;
  {
    const float* lrow = left + (size_t)(b * KK + i) * HH;
    for (int idx = t; idx < NBINS * HH; idx += 256) {
      int bn = idx / HH, k = idx - bn * HH;
      ld_s[bn][k] = lrow[k] + demb[bn * HH + k];
    }
  }
  short8 wo_f[5];
  #pragma unroll
  for (int ks = 0; ks < 5; ++ks)
    wo_f[ks] = *(const short8*)(wo + lr * KP + ks * 32 + lg * 8);

  short8 pw[3];
  #pragma unroll
  for (int c = 0; c < 3; ++c) {
    int idx = t + c * 256;
    if (idx < 640) pw[c] = *(const short8*)(wt + idx * 8);
  }
  #pragma unroll
  for (int c = 0; c < 3; ++c) {
    int idx = t + c * 256;
    if (idx < 640) *(short8*)&wtbuf[0][idx * 8] = pw[c];
  }
  #pragma unroll
  for (int c = 0; c < 3; ++c) {
    int idx = t + c * 256;
    if (idx < 640) pw[c] = *(const short8*)(wt + 5120 + idx * 8);
  }
  __syncthreads();   // (1) buf0 + ld_s ready

  // ---- build A-fragments in registers
  int jr = w * 16 + lr;
  int binr = bins[jr];
  const float* rrow = right + (size_t)(b * KK + j0 + jr) * HH;
  const float* ldr = &ld_s[binr][0];
  short8 afr[5];
  #pragma unroll
  for (int ks = 0; ks < 5; ++ks) {
    int k0 = ks * 32 + lg * 8;
    unsigned pk[4];
    if (k0 + 8 <= HH) {
      #pragma unroll
      for (int e = 0; e < 4; ++e) {
        float2 rv = *(const float2*)(rrow + k0 + e * 2);
        float v0 = fmaxf(ldr[k0 + e * 2]     + rv.x, 0.f);
        float v1 = fmaxf(ldr[k0 + e * 2 + 1] + rv.y, 0.f);
        pk[e] = f2bfu(v0) | (f2bfu(v1) << 16);
      }
    } else if (k0 < HH) {          // k0 == 144: elements 0..5 valid
      #pragma unroll
      for (int e = 0; e < 4; ++e) {
        int k = k0 + e * 2;
        float v0 = 0.f, v1 = 0.f;
        if (k < HH) {
          float2 rv = *(const float2*)(rrow + k);
          v0 = fmaxf(ldr[k] + rv.x, 0.f);
          if (k + 1 < HH) v1 = fmaxf(ldr[k + 1] + rv.y, 0.f);
        }
        pk[e] = f2bfu(v0) | (f2bfu(v1) << 16);
      }
    } else {
      pk[0] = pk[1] = pk[2] = pk[3] = 0;
    }
    int4 tmp; tmp.x = (int)pk[0]; tmp.y = (int)pk[1]; tmp.z = (int)pk[2]; tmp.w = (int)pk[3];
    afr[ks] = *(short8*)&tmp;
  }

  // ---- GEMM1: 5 slices of 32 n-rows, double-buffered
  f32x4 acc[10];
  #pragma unroll
  for (int m = 0; m < 10; ++m) acc[m] = (f32x4){0.f, 0.f, 0.f, 0.f};

  #pragma unroll
  for (int s = 0; s < 5; ++s) {
    if (s > 0) __syncthreads();     // prev slice reads done; buf[s&1] ready
    if (s + 1 < 5) {
      #pragma unroll
      for (int c = 0; c < 3; ++c) {
        int idx = t + c * 256;
        if (idx < 640) *(short8*)&wtbuf[(s + 1) & 1][idx * 8] = pw[c];
      }
      if (s + 2 < 5) {
        #pragma unroll
        for (int c = 0; c < 3; ++c) {
          int idx = t + c * 256;
          if (idx < 640) pw[c] = *(const short8*)(wt + (s + 2) * 5120 + idx * 8);
        }
      }
    }
    const short* bufp = &wtbuf[s & 1][0];
    #pragma unroll
    for (int ks = 0; ks < 5; ++ks) {
      short8 a = afr[ks];
      #pragma unroll
      for (int ntp = 0; ntp < 2; ++ntp) {
        short8 bf = *(const short8*)(bufp + (ntp * 16 + lr) * KP + ks * 32 + lg * 8);
        acc[s * 2 + ntp] = __builtin_amdgcn_mfma_f32_16x16x32_bf16(a, bf, acc[s * 2 + ntp], 0, 0, 0);
      }
    }
  }
  __syncthreads();   // (6) all wt reads done

  // ---- h1 = relu(acc + b_h) -> bf16 into wtbuf region [64][160]
  short* h1 = &wtbuf[0][0];
  #pragma unroll
  for (int m = 0; m < 10; ++m) {
    int col = (m >> 1) * 32 + (m & 1) * 16 + lr;
    float bh = bh_s[col];
    #pragma unroll
    for (int q = 0; q < 4; ++q) {
      int row = w * 16 + lg * 4 + q;
      float hv = fmaxf(acc[m][q] + bh, 0.f);
      h1[row * KP + col] = (short)f2bfu(hv);
    }
  }
  __syncthreads();   // (7) h1 ready

  // ---- GEMM2: h1 @ wo
  f32x4 acc2 = (f32x4){0.f, 0.f, 0.f, 0.f};
  #pragma unroll
  for (int ks = 0; ks < 5; ++ks) {
    short8 a = *(const short8*)(h1 + (w * 16 + lr) * KP + ks * 32 + lg * 8);
    acc2 = __builtin_amdgcn_mfma_f32_16x16x32_bf16(a, wo_f[ks], acc2, 0, 0, 0);
  }

  // ---- epilogue
  float ssi = ss[b * KK + i];
  float* out_s = (float*)&ld_s[0][0];
  if (lr < LL) {
    float bo = b_out[lr];
    #pragma unroll
    for (int q = 0; q < 4; ++q) {
      int row = w * 16 + lg * 4 + q;
      out_s[row * 12 + lr] = acc2[q] + bo + ssi + ssj_s[row];
    }
  }
  __syncthreads();   // (8)
  size_t base = ((size_t)(b * KK + i) * KK + j0) * LL;
  for (int idx = t; idx < 64 * LL; idx += 256) {
    int j = idx / LL, ll2 = idx - j * LL;
    rel[base + idx] = out_s[j * 12 + ll2];
  }
}

// ---------------- ctxt via MFMA (j-tile 32, 192 blocks, reg prefetch) ----------------
__global__ __launch_bounds__(256) void k_ctxt_mfma(
    const short* __restrict__ probsT, const short* __restrict__ updT,
    const float* __restrict__ a_w, const float* __restrict__ span_len,
    float* __restrict__ ctxt, short* __restrict__ ctxbf)
{
  int bidx = blockIdx.x;              // B * 8 * 12 = 192
  int b = bidx / 96;
  int r = bidx - b * 96;
  int jt = r / 12, dt = r - jt * 12;
  int j0 = jt * 32, d0 = dt * 64;

  __shared__ short Bs[64][BPAD];      // updT tile [d][i]
  __shared__ short As[32][BPAD];      // probsT tile [j][i] for current l

  int t = threadIdx.x, l = t & 63, w = t >> 6, lr = l & 15, lg = l >> 4;
  int wr = w >> 1, wc = w & 1;

  for (int s = 0; s < 8; ++s) {
    int idx = t + s * 256;
    int row = idx >> 5, c = idx & 31;
    *(short8*)&Bs[row][c * 8] =
        *(const short8*)(updT + ((size_t)(b * DD + d0 + row)) * KK + c * 8);
  }

  short8 pa[4];
  #pragma unroll
  for (int s = 0; s < 4; ++s) {
    int idx = t + s * 256;
    int row = idx >> 5, c = idx & 31;
    pa[s] = *(const short8*)(probsT + (((size_t)(b * LL + 0)) * KK + j0 + row) * KK + c * 8);
  }

  f32x4 accF[2];
  accF[0] = (f32x4){0.f, 0.f, 0.f, 0.f};
  accF[1] = (f32x4){0.f, 0.f, 0.f, 0.f};

  for (int ll = 0; ll < LL; ++ll) {
    __syncthreads();
    #pragma unroll
    for (int s = 0; s < 4; ++s) {
      int idx = t + s * 256;
      int row = idx >> 5, c = idx & 31;
      *(short8*)&As[row][c * 8] = pa[s];
    }
    if (ll + 1 < LL) {
      #pragma unroll
      for (int s = 0; s < 4; ++s) {
        int idx = t + s * 256;
        int row = idx >> 5, c = idx & 31;
        pa[s] = *(const short8*)(probsT + (((size_t)(b * LL + ll + 1)) * KK + j0 + row) * KK + c * 8);
      }
    }
    float awl[2];
    #pragma unroll
    for (int nt = 0; nt < 2; ++nt) awl[nt] = a_w[ll * DD + d0 + wc * 32 + nt * 16 + lr];
    __syncthreads();

    f32x4 accL[2];
    accL[0] = (f32x4){0.f, 0.f, 0.f, 0.f};
    accL[1] = (f32x4){0.f, 0.f, 0.f, 0.f};
    #pragma unroll
    for (int ks = 0; ks < 8; ++ks) {
      short8 a = *(short8*)&As[wr * 16 + lr][ks * 32 + lg * 8];
      #pragma unroll
      for (int nt = 0; nt < 2; ++nt) {
        short8 bf = *(short8*)&Bs[wc * 32 + nt * 16 + lr][ks * 32 + lg * 8];
        accL[nt] = __builtin_amdgcn_mfma_f32_16x16x32_bf16(a, bf, accL[nt], 0, 0, 0);
      }
    }
    #pragma unroll
    for (int nt = 0; nt < 2; ++nt)
      #pragma unroll
      for (int q = 0; q < 4; ++q)
        accF[nt][q] = fmaf(awl[nt], accL[nt][q], accF[nt][q]);
  }

  float inv = 1.f / span_len[b];
  int rowb = j0 + wr * 16 + lg * 4;
  #pragma unroll
  for (int nt = 0; nt < 2; ++nt) {
    int col = d0 + wc * 32 + nt * 16 + lr;
    #pragma unroll
    for (int q = 0; q < 4; ++q) {
      size_t off = (size_t)(b * KK + rowb + q) * DD + col;
      float v = accF[nt][q] * inv;
      ctxt[off] = v;
      ctxbf[off] = (short)f2bfu(v);
    }
  }
}

// ---------------- gate via MFMA (32x64 tiles, K-step 64, fused updT write) ----------------
__global__ __launch_bounds__(256) void k_gate_mfma(
    const short* __restrict__ updbf, const short* __restrict__ ctxbf,
    const short* __restrict__ gwt, const float* __restrict__ gate_b,
    const float* __restrict__ ctxt, float* __restrict__ upd,
    short* __restrict__ nxtbf, short* __restrict__ updT)
{
  int rb = blockIdx.x / 12, cb = blockIdx.x - rb * 12;
  int row0 = rb * 32, col0 = cb * 64;
  __shared__ short As[32][GWP];
  __shared__ short Bs[64][GWP];
  int t = threadIdx.x, l = t & 63, w = t >> 6, lr = l & 15, lg = l >> 4;
  int wr = w >> 1, wc = w & 1;

  int ar = t >> 3, ac = t & 7;
  int b1 = t + 256;

  f32x4 acc[2];
  acc[0] = (f32x4){0.f, 0.f, 0.f, 0.f};
  acc[1] = (f32x4){0.f, 0.f, 0.f, 0.f};

  short8 pa = *(const short8*)(updbf + (size_t)(row0 + ar) * DD + ac * 8);
  short8 pb0 = *(const short8*)(gwt + (size_t)(col0 + (t >> 3)) * (2 * DD) + (t & 7) * 8);
  short8 pb1 = *(const short8*)(gwt + (size_t)(col0 + (b1 >> 3)) * (2 * DD) + (b1 & 7) * 8);

  for (int ks = 0; ks < 24; ++ks) {
    __syncthreads();
    *(short8*)&As[ar][ac * 8] = pa;
    *(short8*)&Bs[t >> 3][(t & 7) * 8] = pb0;
    *(short8*)&Bs[b1 >> 3][(b1 & 7) * 8] = pb1;
    if (ks + 1 < 24) {
      int k0 = (ks + 1) * 64;
      int ka = k0 + ac * 8;
      const short* asrc = (ka < DD) ? (updbf + (size_t)(row0 + ar) * DD + ka)
                                    : (ctxbf + (size_t)(row0 + ar) * DD + ka - DD);
      pa  = *(const short8*)asrc;
      pb0 = *(const short8*)(gwt + (size_t)(col0 + (t >> 3)) * (2 * DD) + k0 + (t & 7) * 8);
      pb1 = *(const short8*)(gwt + (size_t)(col0 + (b1 >> 3)) * (2 * DD) + k0 + (b1 & 7) * 8);
    }
    __syncthreads();
    #pragma unroll
    for (int ksub = 0; ksub < 2; ++ksub) {
      short8 a = *(short8*)&As[wr * 16 + lr][ksub * 32 + lg * 8];
      #pragma unroll
      for (int nt = 0; nt < 2; ++nt) {
        short8 bf = *(short8*)&Bs[wc * 32 + nt * 16 + lr][ksub * 32 + lg * 8];
        acc[nt] = __builtin_amdgcn_mfma_f32_16x16x32_bf16(a, bf, acc[nt], 0, 0, 0);
      }
    }
  }
  int rowb = row0 + wr * 16 + lg * 4;
  int bb = rowb >> 8, ii = rowb & 255;
  #pragma unroll
  for (int nt = 0; nt < 2; ++nt) {
    int col = col0 + wc * 32 + nt * 16 + lr;
    float gb = gate_b[col];
    s16x4 tw;
    #pragma unroll
    for (int q = 0; q < 4; ++q) {
      size_t off = (size_t)(rowb + q) * DD + col;
      float x = acc[nt][q] + gb;
      float g = 1.f / (1.f + expf(-x));
      float o = g * upd[off] + (1.f - g) * ctxt[off];
      upd[off] = o;
      short bv = (short)f2bfu(o);
      nxtbf[off] = bv;
      tw[q] = bv;
    }
    *(s16x4*)(updT + ((size_t)(bb * DD + col)) * KK + ii) = tw;
  }
}

// ---------------- scatter ----------------
__global__ void k_scatter(const float* __restrict__ upd,
                          const int* __restrict__ prune_idx,
                          const float* __restrict__ span_len,
                          float* __restrict__ out_all)
{
  int b = blockIdx.x / KK;
  int k = blockIdx.x - b * KK;
  if ((float)k < span_len[b]) {
    int dst = prune_idx[b * KK + k];
    const float4* src = (const float4*)(upd + ((size_t)(b * KK + k)) * DD);
    float4* d = (float4*)(out_all + ((size_t)b * NN + dst) * DD);
    for (int idx = threadIdx.x; idx < DD / 4; idx += blockDim.x) d[idx] = src[idx];
  }
}

extern "C" void kernel_launch(void* const* d_in, const int* in_sizes, int n_in,
                              void* d_out, int out_size, void* d_ws, size_t ws_size,
                              hipStream_t stream)
{
  (void)in_sizes; (void)n_in; (void)out_size; (void)ws_size;
  const float* all_span = (const float*)d_in[0];
  const float* upd_in   = (const float*)d_in[1];
  const float* mask     = (const float*)d_in[2];
  const float* span_len = (const float*)d_in[3];
  const int*   span_beg = (const int*)d_in[4];
  const int*   prune    = (const int*)d_in[6];
  const float* w_left   = (const float*)d_in[7];
  const float* b_left   = (const float*)d_in[8];
  const float* w_right  = (const float*)d_in[9];
  const float* b_right  = (const float*)d_in[10];
  const float* dist_emb = (const float*)d_in[11];
  const float* w_h      = (const float*)d_in[12];
  const float* b_h      = (const float*)d_in[13];
  const float* w_out    = (const float*)d_in[14];
  const float* b_out    = (const float*)d_in[15];
  const float* a_w      = (const float*)d_in[16];
  const float* gate_w   = (const float*)d_in[17];
  const float* gate_b   = (const float*)d_in[18];
  const float* pr_w     = (const float*)d_in[19];
  const float* pr_b     = (const float*)d_in[20];

  float* out_all = (float*)d_out;
  float* out_upd = out_all + (size_t)BB * NN * DD;
  float* out_rel = out_upd + (size_t)BB * KK * DD;

  float* ws     = (float*)d_ws;
  float* left   = ws;                                   // 512*150
  float* right  = left + (size_t)BB * KK * HH;          // 512*150 (+64 pad via ssv)
  float* ssv    = right + (size_t)BB * KK * HH + 64;    // 512
  float* ctxt   = ssv + (size_t)BB * KK;                // 512*768
  short* wt_bf  = (short*)(ctxt + (size_t)BB * KK * DD);// 160*160
  short* wo_bf  = wt_bf + KP * KP;                      // 16*160
  short* updbf0 = wo_bf + 16 * KP;                      // 512*768
  short* updbf1 = updbf0 + (size_t)BB * KK * DD;
  short* ctxbf  = updbf1 + (size_t)BB * KK * DD;
  short* gwt    = ctxbf + (size_t)BB * KK * DD;         // 768*1536
  short* wlrt   = gwt + (size_t)DD * 2 * DD;            // 320*768
  short* probsT = wlrt + (size_t)2 * KP * DD;           // 2*11*256*256
  short* updT   = probsT + (size_t)BB * LL * KK * KK;   // 2*768*256

  const int nupd = BB * KK * DD;

  hipMemcpyAsync(out_all, all_span, sizeof(float) * (size_t)BB * NN * DD,
                 hipMemcpyDeviceToDevice, stream);
  hipMemcpyAsync(out_upd, upd_in, sizeof(float) * (size_t)BB * KK * DD,
                 hipMemcpyDeviceToDevice, stream);
  k_prep<<<(KP * KP + 16 * KP + 255) / 256, 256, 0, stream>>>(w_h, w_out, wt_bf, wo_bf);
  k_cvt<<<(nupd + 255) / 256, 256, 0, stream>>>(upd_in, updbf0, nupd);
  k_tr_gw<<<48 * 24, 256, 0, stream>>>(gate_w, gwt);
  k_tr_wlr<<<24 * 10, 256, 0, stream>>>(w_left, w_right, wlrt);
  k_tr_upd<<<BB * 8 * 24, 256, 0, stream>>>(upd_in, updT);

  k_proj_mfma<<<16, 256, 0, stream>>>(updbf0, wlrt, b_left, b_right, left, right);
  k_ss<<<BB * KK / 4, 256, 0, stream>>>(out_upd, pr_w, pr_b, ssv);
  k_pair_mfma<<<BB * KK * 4, 256, 0, stream>>>(left, right, ssv, span_beg, dist_emb,
                                               wt_bf, wo_bf, b_h, b_out, out_rel);

  for (int p = 0; p < 2; ++p) {
    short* cur_bf = (p == 0) ? updbf0 : updbf1;
    short* nxt_bf = (p == 0) ? updbf1 : updbf0;
    k_ptr<<<BB * 8 * 8, 256, 0, stream>>>(out_rel, mask, probsT);
    k_ctxt_mfma<<<BB * 8 * 12, 256, 0, stream>>>(probsT, updT, a_w, span_len, ctxt, ctxbf);
    k_gate_mfma<<<16 * 12, 256, 0, stream>>>(cur_bf, ctxbf, gwt, gate_b, ctxt,
                                             out_upd, nxt_bf, updT);
    k_proj_mfma<<<16, 256, 0, stream>>>(nxt_bf, wlrt, b_left, b_right, left, right);
    k_ss<<<BB * KK / 4, 256, 0, stream>>>(out_upd, pr_w, pr_b, ssv);
    k_pair_mfma<<<BB * KK * 4, 256, 0, stream>>>(left, right, ssv, span_beg, dist_emb,
                                                 wt_bf, wo_bf, b_h, b_out, out_rel);
  }
  k_scatter<<<BB * KK, 192, 0, stream>>>(out_upd, prune, span_len, out_all);
}